// Round 2
// baseline (2433.354 us; speedup 1.0000x reference)
//
#include <hip/hip_runtime.h>
#include <math.h>

#define V_SIZE 50257
#define EMB 512
#define HID 512
#define NB 32
#define TT 128
#define NSTEP 127
#define G3H 1536
#define MROWS 4064   // NSTEP*NB
#define MPAD 4096
#define VPAD 50304   // 393*128
#define NT_V 393
#define NBLK_GRU 32

typedef __attribute__((ext_vector_type(4))) float f32x4;
typedef __attribute__((ext_vector_type(8))) __bf16 bf16x8;
typedef __attribute__((ext_vector_type(4))) __bf16 bf16x4;

// async global->LDS, 16B per lane; lptr must be wave-uniform (HW adds lane*16)
__device__ __forceinline__ void async16(const __bf16* g, __bf16* l) {
    __builtin_amdgcn_global_load_lds(
        (const __attribute__((address_space(1))) void*)g,
        (__attribute__((address_space(3))) void*)l, 16, 0, 0);
}

// ---------------- prep kernels ----------------

__global__ void k_prep_emit(const float* __restrict__ src, __bf16* __restrict__ dst) {
    size_t total4 = (size_t)VPAD * 512 / 4;
    size_t real4  = (size_t)V_SIZE * 512 / 4;
    for (size_t i4 = (size_t)blockIdx.x * blockDim.x + threadIdx.x; i4 < total4;
         i4 += (size_t)gridDim.x * blockDim.x) {
        float4 v = (i4 < real4) ? ((const float4*)src)[i4] : make_float4(0.f,0.f,0.f,0.f);
        bf16x4 o = {(__bf16)v.x, (__bf16)v.y, (__bf16)v.z, (__bf16)v.w};
        ((bf16x4*)dst)[i4] = o;
    }
}

__global__ void k_prep_wih(const float* __restrict__ src, __bf16* __restrict__ dst) {
    size_t total4 = (size_t)G3H * 512 / 4;
    for (size_t i4 = (size_t)blockIdx.x * blockDim.x + threadIdx.x; i4 < total4;
         i4 += (size_t)gridDim.x * blockDim.x) {
        float4 v = ((const float4*)src)[i4];
        bf16x4 o = {(__bf16)v.x, (__bf16)v.y, (__bf16)v.z, (__bf16)v.w};
        ((bf16x4*)dst)[i4] = o;
    }
}

// embedding gather -> Xb bf16 [MPAD,512]; zero pad rows of Xb and Hs
__global__ void k_prep_x(const int* __restrict__ words, const float* __restrict__ embed,
                         __bf16* __restrict__ Xb, __bf16* __restrict__ Hs) {
    int s = blockIdx.x;   // 0..127
    int n = blockIdx.y;   // 0..31
    int tid = threadIdx.x; // 128
    if (s < NSTEP) {
        int w = words[n * TT + s];
        size_t row = (size_t)(s * NB + n);
        const float4* src = (const float4*)(embed + (size_t)w * EMB);
        bf16x4* dst = (bf16x4*)(Xb + row * EMB);
        for (int c = tid; c < EMB / 4; c += 128) {
            float4 v = src[c];
            bf16x4 o = {(__bf16)v.x, (__bf16)v.y, (__bf16)v.z, (__bf16)v.w};
            dst[c] = o;
        }
    } else {
        size_t row = (size_t)(MROWS + n);
        bf16x4 z = {(__bf16)0.f, (__bf16)0.f, (__bf16)0.f, (__bf16)0.f};
        for (int c = tid; c < EMB / 4; c += 128) {
            ((bf16x4*)(Xb + row * EMB))[c] = z;
            ((bf16x4*)(Hs + row * HID))[c] = z;
        }
    }
}

// Hbuf[0] = bf16(h0); zero barrier flags
__global__ void k_prep_h0(const float* __restrict__ h0, __bf16* __restrict__ Hbuf,
                          int* __restrict__ flags) {
    int b = blockIdx.x;
    if (b < NB) {
        for (int k = threadIdx.x; k < HID; k += 256)
            Hbuf[b * HID + k] = (__bf16)h0[b * HID + k];
    } else {
        if (threadIdx.x < 128) flags[threadIdx.x] = 0;
    }
}

// ---------------- m97-style MFMA mainloop: C[128m x 128n], K=512, bf16 K-major ----------------

__device__ __forceinline__ void mm128(const __bf16* __restrict__ A,
                                      const __bf16* __restrict__ B,
                                      int mBase, int nBase, f32x4 acc[4][4],
                                      __bf16* As, __bf16* Bs) {
    const int tid = threadIdx.x;
    const int lane = tid & 63, wave = tid >> 6;
    const int wm = wave >> 1, wn = wave & 1;
    const int lane15 = lane & 15, quad = lane >> 4;
    for (int kc = 0; kc < 512; kc += 64) {
        __syncthreads();
#pragma unroll
        for (int i = 0; i < 4; ++i) {
            int c = (wave * 4 + i) * 64 + lane;   // 16B chunk id, 0..1023
            int row = c >> 3, k8 = (c & 7) << 3;  // 8 chunks per 64-elem row
            async16(A + (size_t)(mBase + row) * 512 + kc + k8, As + (wave * 4 + i) * 512);
            async16(B + (size_t)(nBase + row) * 512 + kc + k8, Bs + (wave * 4 + i) * 512);
        }
        __syncthreads();   // drains vmcnt (global_load_lds) per m97 structure
#pragma unroll
        for (int ks = 0; ks < 64; ks += 32) {
            bf16x8 a4[4], b4[4];
#pragma unroll
            for (int mi = 0; mi < 4; ++mi)
                a4[mi] = *(const bf16x8*)(As + (wm * 64 + mi * 16 + lane15) * 64 + ks + quad * 8);
#pragma unroll
            for (int ni = 0; ni < 4; ++ni)
                b4[ni] = *(const bf16x8*)(Bs + (wn * 64 + ni * 16 + lane15) * 64 + ks + quad * 8);
#pragma unroll
            for (int mi = 0; mi < 4; ++mi)
#pragma unroll
                for (int ni = 0; ni < 4; ++ni)
                    acc[mi][ni] = __builtin_amdgcn_mfma_f32_16x16x32_bf16(
                        a4[mi], b4[ni], acc[mi][ni], 0, 0, 0);
        }
    }
}

// gi = Xb @ W_ih^T + b_ih (+ b_hh for r,z gates)  -> fp32 [MPAD][1536]
__global__ __launch_bounds__(256) void k_gemm_gi(const __bf16* __restrict__ Xb,
                                                 const __bf16* __restrict__ Wihb,
                                                 const float* __restrict__ b_ih,
                                                 const float* __restrict__ b_hh,
                                                 float* __restrict__ gi) {
    __shared__ __align__(16) __bf16 As[128 * 64];
    __shared__ __align__(16) __bf16 Bs[128 * 64];
    f32x4 acc[4][4];
    f32x4 z = {0.f, 0.f, 0.f, 0.f};
#pragma unroll
    for (int mi = 0; mi < 4; ++mi)
#pragma unroll
        for (int ni = 0; ni < 4; ++ni) acc[mi][ni] = z;
    int mBase = blockIdx.x * 128, nBase = blockIdx.y * 128;
    mm128(Xb, Wihb, mBase, nBase, acc, As, Bs);
    const int tid = threadIdx.x, lane = tid & 63, wave = tid >> 6;
    const int wm = wave >> 1, wn = wave & 1, lane15 = lane & 15, quad = lane >> 4;
#pragma unroll
    for (int ni = 0; ni < 4; ++ni) {
        int col = nBase + wn * 64 + ni * 16 + lane15;
        float bias = b_ih[col] + (col < 1024 ? b_hh[col] : 0.0f);
#pragma unroll
        for (int mi = 0; mi < 4; ++mi) {
            int rowb = wm * 64 + mi * 16 + quad * 4;
#pragma unroll
            for (int r = 0; r < 4; ++r) {
                int m = mBase + rowb + r;
                gi[(size_t)m * G3H + col] = acc[mi][ni][r] + bias;
            }
        }
    }
}

// emit GEMM with fused per-tile logsumexp partials
__global__ __launch_bounds__(256) void k_gemm_emit(const __bf16* __restrict__ Hs,
                                                   const __bf16* __restrict__ Wemb,
                                                   const float* __restrict__ emit_b,
                                                   float2* __restrict__ partials) {
    __shared__ __align__(16) __bf16 As[128 * 64];
    __shared__ __align__(16) __bf16 Bs[128 * 64];
    __shared__ float2 red[128][2];
    f32x4 acc[4][4];
    f32x4 z = {0.f, 0.f, 0.f, 0.f};
#pragma unroll
    for (int mi = 0; mi < 4; ++mi)
#pragma unroll
        for (int ni = 0; ni < 4; ++ni) acc[mi][ni] = z;
    int mBase = blockIdx.x * 128;
    int nT = blockIdx.y;
    int nBase = nT * 128;
    mm128(Hs, Wemb, mBase, nBase, acc, As, Bs);
    const int tid = threadIdx.x, lane = tid & 63, wave = tid >> 6;
    const int wm = wave >> 1, wn = wave & 1, lane15 = lane & 15, quad = lane >> 4;
    const float NINF = -__builtin_inff();
    float bv[4];
    bool valid[4];
#pragma unroll
    for (int ni = 0; ni < 4; ++ni) {
        int col = nBase + wn * 64 + ni * 16 + lane15;
        valid[ni] = (col < V_SIZE);
        bv[ni] = valid[ni] ? emit_b[col] : 0.0f;
    }
#pragma unroll
    for (int mi = 0; mi < 4; ++mi) {
#pragma unroll
        for (int r = 0; r < 4; ++r) {
            float vals[4];
            float vmax = NINF;
#pragma unroll
            for (int ni = 0; ni < 4; ++ni) {
                float v = acc[mi][ni][r] + bv[ni];
                if (!valid[ni]) v = NINF;
                vals[ni] = v;
                vmax = fmaxf(vmax, v);
            }
#pragma unroll
            for (int off = 1; off < 16; off <<= 1)
                vmax = fmaxf(vmax, __shfl_xor(vmax, off));
            float ssum = 0.f;
#pragma unroll
            for (int ni = 0; ni < 4; ++ni) ssum += expf(vals[ni] - vmax);
#pragma unroll
            for (int off = 1; off < 16; off <<= 1) ssum += __shfl_xor(ssum, off);
            if (lane15 == 0) {
                int rl = wm * 64 + mi * 16 + quad * 4 + r;
                red[rl][wn] = make_float2(vmax, ssum);
            }
        }
    }
    __syncthreads();
    if (tid < 128) {
        float2 a = red[tid][0], b2 = red[tid][1];
        float M = fmaxf(a.x, b2.x);
        float S = a.y * expf(a.x - M) + b2.y * expf(b2.x - M);
        partials[(size_t)(mBase + tid) * NT_V + nT] = make_float2(M, S);
    }
}

// ---------------- persistent GRU: all 127 steps in one launch ----------------
// 32 blocks, block blk owns h columns [blk*16, blk*16+16). W_hh slice bf16 in LDS.
// h master copy fp32 in LDS (z*h chain stays fp32); bf16 only in the gate dots.
__global__ __launch_bounds__(256) void k_gru_persist(
    const float* __restrict__ W_hh, const float* __restrict__ gi,
    const float* __restrict__ b_hh, const float* __restrict__ h0,
    __bf16* __restrict__ Hbuf,   // [2][32][512] bf16 ping-pong
    __bf16* __restrict__ Hs,     // [MPAD][512] bf16
    float* __restrict__ Hfin,    // [32][512] fp32
    int* __restrict__ flags)     // [128]
{
    const int blk = blockIdx.x;
    const int j0 = blk * 16;
    const int tid = threadIdx.x;
    const int lane = tid & 63, wave = tid >> 6;
    const int lane15 = lane & 15, quad = lane >> 4;

    __shared__ __align__(16) __bf16 Wl[48 * 520];  // rows: g*16+jc, padded stride (2-way-free banks)
    __shared__ float Cred[3][32][16];
    __shared__ float Hloc[32][16];

    // load + convert W_hh slice: row rr=g*16+jc  <- W_hh[g*512 + j0 + jc][:]
    for (int idx = tid; idx < 48 * 128; idx += 256) {
        int rr = idx >> 7, k4 = (idx & 127) << 2;
        int g = rr >> 4, jc = rr & 15;
        float4 v = *(const float4*)(W_hh + (size_t)(g * 512 + j0 + jc) * 512 + k4);
        __bf16* d = &Wl[rr * 520 + k4];
        d[0] = (__bf16)v.x; d[1] = (__bf16)v.y; d[2] = (__bf16)v.z; d[3] = (__bf16)v.w;
    }
    for (int u = tid; u < 512; u += 256)
        Hloc[u >> 4][u & 15] = h0[(size_t)(u >> 4) * HID + j0 + (u & 15)];

    const int m0 = tid >> 4, jc0 = tid & 15;   // unit 0: (m0, jc0); unit 1: (m0+16, jc0)
    const int m1 = m0 + 16;
    const float bhn = b_hh[1024 + j0 + jc0];
    const int k0 = wave * 128;                 // k-split across 4 waves
    __syncthreads();

    for (int s = 0; s < NSTEP; ++s) {
        // prefetch gi early (consumed after MFMA)
        const float* g0 = gi + (size_t)(s * NB + m0) * G3H + j0 + jc0;
        const float* g1 = gi + (size_t)(s * NB + m1) * G3H + j0 + jc0;
        float ir0 = g0[0], iz0 = g0[512], in0 = g0[1024];
        float ir1 = g1[0], iz1 = g1[512], in1 = g1[1024];

        for (int u = tid; u < 3 * 32 * 16; u += 256) ((float*)Cred)[u] = 0.f;
        __syncthreads();

        const __bf16* hb = Hbuf + (size_t)(s & 1) * NB * HID;
        f32x4 acc[2][3];
        f32x4 zz = {0.f, 0.f, 0.f, 0.f};
#pragma unroll
        for (int mt = 0; mt < 2; ++mt)
#pragma unroll
            for (int g = 0; g < 3; ++g) acc[mt][g] = zz;
#pragma unroll
        for (int ks = 0; ks < 128; ks += 32) {
            bf16x8 a0 = *(const bf16x8*)(hb + (size_t)lane15 * HID + k0 + ks + quad * 8);
            bf16x8 a1 = *(const bf16x8*)(hb + (size_t)(16 + lane15) * HID + k0 + ks + quad * 8);
#pragma unroll
            for (int g = 0; g < 3; ++g) {
                bf16x8 b4 = *(const bf16x8*)(&Wl[(g * 16 + lane15) * 520 + k0 + ks + quad * 8]);
                acc[0][g] = __builtin_amdgcn_mfma_f32_16x16x32_bf16(a0, b4, acc[0][g], 0, 0, 0);
                acc[1][g] = __builtin_amdgcn_mfma_f32_16x16x32_bf16(a1, b4, acc[1][g], 0, 0, 0);
            }
        }
#pragma unroll
        for (int mt = 0; mt < 2; ++mt)
#pragma unroll
            for (int g = 0; g < 3; ++g)
#pragma unroll
                for (int r = 0; r < 4; ++r)
                    atomicAdd(&Cred[g][mt * 16 + quad * 4 + r][lane15], acc[mt][g][r]);
        __syncthreads();

        // nonlinearity for (m0,jc0) and (m1,jc0)
        {
            float gr = Cred[0][m0][jc0], gz = Cred[1][m0][jc0], gn = Cred[2][m0][jc0];
            float r = 1.f / (1.f + expf(-(ir0 + gr)));
            float zg = 1.f / (1.f + expf(-(iz0 + gz)));
            float nn = tanhf(in0 + r * (gn + bhn));
            float hp = Hloc[m0][jc0];
            float hn = (1.f - zg) * nn + zg * hp;
            Hloc[m0][jc0] = hn;
            __bf16 hb16 = (__bf16)hn;
            Hbuf[(size_t)((s + 1) & 1) * NB * HID + (size_t)m0 * HID + j0 + jc0] = hb16;
            Hs[(size_t)(s * NB + m0) * HID + j0 + jc0] = hb16;
            Hfin[(size_t)m0 * HID + j0 + jc0] = hn;
        }
        {
            float gr = Cred[0][m1][jc0], gz = Cred[1][m1][jc0], gn = Cred[2][m1][jc0];
            float r = 1.f / (1.f + expf(-(ir1 + gr)));
            float zg = 1.f / (1.f + expf(-(iz1 + gz)));
            float nn = tanhf(in1 + r * (gn + bhn));
            float hp = Hloc[m1][jc0];
            float hn = (1.f - zg) * nn + zg * hp;
            Hloc[m1][jc0] = hn;
            __bf16 hb16 = (__bf16)hn;
            Hbuf[(size_t)((s + 1) & 1) * NB * HID + (size_t)m1 * HID + j0 + jc0] = hb16;
            Hs[(size_t)(s * NB + m1) * HID + j0 + jc0] = hb16;
            Hfin[(size_t)m1 * HID + j0 + jc0] = hn;
        }
        __syncthreads();
        // device-scope barrier across the 32 co-resident blocks
        if (tid == 0) {
            __threadfence();  // release: writeback this XCD's L2
            __hip_atomic_fetch_add(&flags[s], 1, __ATOMIC_RELEASE, __HIP_MEMORY_SCOPE_AGENT);
            while (__hip_atomic_load(&flags[s], __ATOMIC_ACQUIRE, __HIP_MEMORY_SCOPE_AGENT) < NBLK_GRU) {}
            __threadfence();  // acquire: invalidate L1/L2 before next step's reads
        }
        __syncthreads();
    }
}

// ---------------- per-row log-likelihood ----------------
__global__ __launch_bounds__(128) void k_row_ll(const float2* __restrict__ partials,
                                                const __bf16* __restrict__ Hs,
                                                const __bf16* __restrict__ Wemb,
                                                const float* __restrict__ emit_b,
                                                const int* __restrict__ words,
                                                float* __restrict__ lls) {
    int s = blockIdx.x, n = blockIdx.y;
    int m = s * NB + n;
    int tid = threadIdx.x;
    int lane = tid & 63, w = tid >> 6;
    __shared__ float sm[2], ss[2], sd[2];
    const float2* prow = partials + (size_t)m * NT_V;
    float M = -__builtin_inff();
    for (int i = tid; i < NT_V; i += 128) M = fmaxf(M, prow[i].x);
#pragma unroll
    for (int off = 1; off < 64; off <<= 1) M = fmaxf(M, __shfl_xor(M, off));
    if (lane == 0) sm[w] = M;
    __syncthreads();
    M = fmaxf(sm[0], sm[1]);
    float S = 0.f;
    for (int i = tid; i < NT_V; i += 128) {
        float2 p = prow[i];
        S += p.y * expf(p.x - M);
    }
#pragma unroll
    for (int off = 1; off < 64; off <<= 1) S += __shfl_xor(S, off);
    if (lane == 0) ss[w] = S;
    __syncthreads();
    S = ss[0] + ss[1];
    int tw = words[n * TT + s + 1];
    float d = 0.f;
    const __bf16* hr = Hs + (size_t)m * HID;
    const __bf16* wr = Wemb + (size_t)tw * HID;
    for (int k = tid; k < HID; k += 128) d += (float)hr[k] * (float)wr[k];
#pragma unroll
    for (int off = 1; off < 64; off <<= 1) d += __shfl_xor(d, off);
    if (lane == 0) sd[w] = d;
    __syncthreads();
    if (tid == 0) {
        float dt = sd[0] + sd[1];
        lls[m] = dt + emit_b[tw] - (M + logf(S));
    }
}

// ---------------- final reduce ----------------
__global__ __launch_bounds__(128) void k_final(const float* __restrict__ lls,
                                               const float* __restrict__ Hfin,
                                               float* __restrict__ out) {
    int n = blockIdx.x;
    int tid = threadIdx.x;
    float s = 0.f;
    for (int i = tid; i < NSTEP; i += 128) s += lls[i * NB + n];
#pragma unroll
    for (int off = 1; off < 64; off <<= 1) s += __shfl_xor(s, off);
    __shared__ float t2[2];
    if ((tid & 63) == 0) t2[tid >> 6] = s;
    __syncthreads();
    if (tid == 0) out[n] = (t2[0] + t2[1]) / (float)NSTEP;
    for (int i = tid; i < HID; i += 128) out[NB + n * HID + i] = Hfin[(size_t)n * HID + i];
}

// ---------------- launch ----------------
extern "C" void kernel_launch(void* const* d_in, const int* in_sizes, int n_in,
                              void* d_out, int out_size, void* d_ws, size_t ws_size,
                              hipStream_t stream) {
    const int*   words   = (const int*)d_in[0];
    const float* hidden0 = (const float*)d_in[1];
    const float* embed_W = (const float*)d_in[2];
    const float* W_ih    = (const float*)d_in[3];
    const float* W_hh    = (const float*)d_in[4];
    const float* b_ih    = (const float*)d_in[5];
    const float* b_hh    = (const float*)d_in[6];
    const float* emit_W  = (const float*)d_in[7];
    const float* emit_b  = (const float*)d_in[8];
    float* out = (float*)d_out;

    char* p = (char*)d_ws;
    auto alloc = [&](size_t bytes) {
        void* r = (void*)p;
        p += (bytes + 255) & ~(size_t)255;
        return r;
    };
    __bf16* emit_Wb = (__bf16*)alloc((size_t)VPAD * 512 * 2);
    __bf16* Xb      = (__bf16*)alloc((size_t)MPAD * 512 * 2);
    __bf16* Wihb    = (__bf16*)alloc((size_t)G3H * 512 * 2);
    float*  gi      = (float*)alloc((size_t)MPAD * G3H * 4);
    __bf16* Hs      = (__bf16*)alloc((size_t)MPAD * 512 * 2);
    __bf16* Hbuf    = (__bf16*)alloc((size_t)2 * NB * HID * 2);
    float*  Hfin    = (float*)alloc((size_t)NB * HID * 4);
    float2* partials= (float2*)alloc((size_t)MPAD * NT_V * 8);
    float*  lls     = (float*)alloc((size_t)MROWS * 4);
    int*    flags   = (int*)alloc(128 * 4);

    k_prep_emit<<<4096, 256, 0, stream>>>(emit_W, emit_Wb);
    k_prep_x<<<dim3(128, 32), 128, 0, stream>>>(words, embed_W, Xb, Hs);
    k_prep_wih<<<768, 256, 0, stream>>>(W_ih, Wihb);
    k_prep_h0<<<NB + 1, 256, 0, stream>>>(hidden0, Hbuf, flags);

    k_gemm_gi<<<dim3(32, 12), 256, 0, stream>>>(Xb, Wihb, b_ih, b_hh, gi);
    k_gru_persist<<<NBLK_GRU, 256, 0, stream>>>(W_hh, gi, b_hh, hidden0, Hbuf, Hs, Hfin, flags);

    k_gemm_emit<<<dim3(32, NT_V), 256, 0, stream>>>(Hs, emit_Wb, emit_b, partials);
    k_row_ll<<<dim3(NSTEP, 32), 128, 0, stream>>>(partials, Hs, emit_Wb, emit_b, words, lls);
    k_final<<<32, 128, 0, stream>>>(lls, Hfin, out);
}

// Round 3
// 1404.907 us; speedup vs baseline: 1.7320x; 1.7320x over previous
//
#include <hip/hip_runtime.h>
#include <math.h>

#define V_SIZE 50257
#define EMB 512
#define HID 512
#define NB 32
#define TT 128
#define NSTEP 127
#define G3H 1536
#define MROWS 4064   // NSTEP*NB
#define MPAD 4096
#define VPAD 50304   // 393*128
#define NT_V 393
#define NBLK_GRU 32
#define FLAG_STRIDE 32   // ints -> 128B per flag

typedef __attribute__((ext_vector_type(4))) float f32x4;
typedef __attribute__((ext_vector_type(8))) __bf16 bf16x8;
typedef __attribute__((ext_vector_type(4))) __bf16 bf16x4;

struct u128 { unsigned long long a, b; };

// async global->LDS, 16B per lane; LDS dst is wave-uniform base + lane*16
__device__ __forceinline__ void async16(const __bf16* g, __bf16* l) {
    __builtin_amdgcn_global_load_lds(
        (const __attribute__((address_space(1))) void*)g,
        (__attribute__((address_space(3))) void*)l, 16, 0, 0);
}

// ---------------- prep kernels ----------------

__global__ void k_prep_emit(const float* __restrict__ src, __bf16* __restrict__ dst) {
    size_t total4 = (size_t)VPAD * 512 / 4;
    size_t real4  = (size_t)V_SIZE * 512 / 4;
    for (size_t i4 = (size_t)blockIdx.x * blockDim.x + threadIdx.x; i4 < total4;
         i4 += (size_t)gridDim.x * blockDim.x) {
        float4 v = (i4 < real4) ? ((const float4*)src)[i4] : make_float4(0.f,0.f,0.f,0.f);
        bf16x4 o = {(__bf16)v.x, (__bf16)v.y, (__bf16)v.z, (__bf16)v.w};
        ((bf16x4*)dst)[i4] = o;
    }
}

__global__ void k_prep_wih(const float* __restrict__ src, __bf16* __restrict__ dst) {
    size_t total4 = (size_t)G3H * 512 / 4;
    for (size_t i4 = (size_t)blockIdx.x * blockDim.x + threadIdx.x; i4 < total4;
         i4 += (size_t)gridDim.x * blockDim.x) {
        float4 v = ((const float4*)src)[i4];
        bf16x4 o = {(__bf16)v.x, (__bf16)v.y, (__bf16)v.z, (__bf16)v.w};
        ((bf16x4*)dst)[i4] = o;
    }
}

// embedding gather -> Xb bf16 [MPAD,512]; zero pad rows of Xb and Hs
__global__ void k_prep_x(const int* __restrict__ words, const float* __restrict__ embed,
                         __bf16* __restrict__ Xb, __bf16* __restrict__ Hs) {
    int s = blockIdx.x;   // 0..127
    int n = blockIdx.y;   // 0..31
    int tid = threadIdx.x; // 128
    if (s < NSTEP) {
        int w = words[n * TT + s];
        size_t row = (size_t)(s * NB + n);
        const float4* src = (const float4*)(embed + (size_t)w * EMB);
        bf16x4* dst = (bf16x4*)(Xb + row * EMB);
        for (int c = tid; c < EMB / 4; c += 128) {
            float4 v = src[c];
            bf16x4 o = {(__bf16)v.x, (__bf16)v.y, (__bf16)v.z, (__bf16)v.w};
            dst[c] = o;
        }
    } else {
        size_t row = (size_t)(MROWS + n);
        bf16x4 z = {(__bf16)0.f, (__bf16)0.f, (__bf16)0.f, (__bf16)0.f};
        for (int c = tid; c < EMB / 4; c += 128) {
            ((bf16x4*)(Xb + row * EMB))[c] = z;
            ((bf16x4*)(Hs + row * HID))[c] = z;
        }
    }
}

// Hbuf[0] = bf16(h0); zero barrier flags
__global__ void k_prep_h0(const float* __restrict__ h0, __bf16* __restrict__ Hbuf,
                          int* __restrict__ flags) {
    int b = blockIdx.x;
    if (b < NB) {
        for (int k = threadIdx.x; k < HID; k += 256)
            Hbuf[b * HID + k] = (__bf16)h0[b * HID + k];
    } else {
        for (int k = threadIdx.x; k < NBLK_GRU * FLAG_STRIDE; k += 256) flags[k] = 0;
    }
}

// ---------------- MFMA mainloop, XOR-swizzled async16 staging ----------------
// C[128m x 128n], K=512, A/B bf16 K-major. LDS rows of 64 elems; 16B chunk at
// physical slot ci holds logical chunk (ci ^ (row&7)) -> 2-way banks on ds_read.

__device__ __forceinline__ void mm128(const __bf16* __restrict__ A,
                                      const __bf16* __restrict__ B,
                                      int mBase, int nBase, f32x4 acc[4][4],
                                      __bf16* As, __bf16* Bs) {
    const int tid = threadIdx.x;
    const int lane = tid & 63, wave = tid >> 6;
    const int wm = wave >> 1, wn = wave & 1;
    const int lane15 = lane & 15, quad = lane >> 4;
    for (int kc = 0; kc < 512; kc += 64) {
        __syncthreads();
#pragma unroll
        for (int i = 0; i < 4; ++i) {
            int c = (wave * 4 + i) * 64 + lane;   // 16B chunk id, 0..1023
            int row = c >> 3, ci = c & 7;
            int cis = ci ^ (row & 7);             // fetch swizzled source chunk
            async16(A + (size_t)(mBase + row) * 512 + kc + (cis << 3), As + (wave * 4 + i) * 512);
            async16(B + (size_t)(nBase + row) * 512 + kc + (cis << 3), Bs + (wave * 4 + i) * 512);
        }
        __syncthreads();
#pragma unroll
        for (int ks = 0; ks < 64; ks += 32) {
            bf16x8 a4[4], b4[4];
#pragma unroll
            for (int mi = 0; mi < 4; ++mi) {
                int row = wm * 64 + mi * 16 + lane15;
                int L = (ks >> 3) + quad;
                a4[mi] = *(const bf16x8*)(As + row * 64 + ((L ^ (row & 7)) << 3));
            }
#pragma unroll
            for (int ni = 0; ni < 4; ++ni) {
                int row = wn * 64 + ni * 16 + lane15;
                int L = (ks >> 3) + quad;
                b4[ni] = *(const bf16x8*)(Bs + row * 64 + ((L ^ (row & 7)) << 3));
            }
#pragma unroll
            for (int mi = 0; mi < 4; ++mi)
#pragma unroll
                for (int ni = 0; ni < 4; ++ni)
                    acc[mi][ni] = __builtin_amdgcn_mfma_f32_16x16x32_bf16(
                        a4[mi], b4[ni], acc[mi][ni], 0, 0, 0);
        }
    }
}

// gi = Xb @ W_ih^T + b_ih (+ b_hh for r,z gates)  -> fp32 [MPAD][1536]
__global__ __launch_bounds__(256) void k_gemm_gi(const __bf16* __restrict__ Xb,
                                                 const __bf16* __restrict__ Wihb,
                                                 const float* __restrict__ b_ih,
                                                 const float* __restrict__ b_hh,
                                                 float* __restrict__ gi) {
    __shared__ __align__(16) __bf16 As[128 * 64];
    __shared__ __align__(16) __bf16 Bs[128 * 64];
    f32x4 acc[4][4];
    f32x4 z = {0.f, 0.f, 0.f, 0.f};
#pragma unroll
    for (int mi = 0; mi < 4; ++mi)
#pragma unroll
        for (int ni = 0; ni < 4; ++ni) acc[mi][ni] = z;
    int mBase = blockIdx.x * 128, nBase = blockIdx.y * 128;
    mm128(Xb, Wihb, mBase, nBase, acc, As, Bs);
    const int tid = threadIdx.x, lane = tid & 63, wave = tid >> 6;
    const int wm = wave >> 1, wn = wave & 1, lane15 = lane & 15, quad = lane >> 4;
#pragma unroll
    for (int ni = 0; ni < 4; ++ni) {
        int col = nBase + wn * 64 + ni * 16 + lane15;
        float bias = b_ih[col] + (col < 1024 ? b_hh[col] : 0.0f);
#pragma unroll
        for (int mi = 0; mi < 4; ++mi) {
            int rowb = wm * 64 + mi * 16 + quad * 4;
#pragma unroll
            for (int r = 0; r < 4; ++r) {
                int m = mBase + rowb + r;
                gi[(size_t)m * G3H + col] = acc[mi][ni][r] + bias;
            }
        }
    }
}

// emit GEMM with fused per-tile logsumexp partials
__global__ __launch_bounds__(256) void k_gemm_emit(const __bf16* __restrict__ Hs,
                                                   const __bf16* __restrict__ Wemb,
                                                   const float* __restrict__ emit_b,
                                                   float2* __restrict__ partials) {
    __shared__ __align__(16) __bf16 As[128 * 64];
    __shared__ __align__(16) __bf16 Bs[128 * 64];
    __shared__ float2 red[128][2];
    f32x4 acc[4][4];
    f32x4 z = {0.f, 0.f, 0.f, 0.f};
#pragma unroll
    for (int mi = 0; mi < 4; ++mi)
#pragma unroll
        for (int ni = 0; ni < 4; ++ni) acc[mi][ni] = z;
    int mBase = blockIdx.x * 128;
    int nT = blockIdx.y;
    int nBase = nT * 128;
    mm128(Hs, Wemb, mBase, nBase, acc, As, Bs);
    const int tid = threadIdx.x, lane = tid & 63, wave = tid >> 6;
    const int wm = wave >> 1, wn = wave & 1, lane15 = lane & 15, quad = lane >> 4;
    const float NINF = -__builtin_inff();
    float bv[4];
    bool valid[4];
#pragma unroll
    for (int ni = 0; ni < 4; ++ni) {
        int col = nBase + wn * 64 + ni * 16 + lane15;
        valid[ni] = (col < V_SIZE);
        bv[ni] = valid[ni] ? emit_b[col] : 0.0f;
    }
#pragma unroll
    for (int mi = 0; mi < 4; ++mi) {
#pragma unroll
        for (int r = 0; r < 4; ++r) {
            float vals[4];
            float vmax = NINF;
#pragma unroll
            for (int ni = 0; ni < 4; ++ni) {
                float v = acc[mi][ni][r] + bv[ni];
                if (!valid[ni]) v = NINF;
                vals[ni] = v;
                vmax = fmaxf(vmax, v);
            }
#pragma unroll
            for (int off = 1; off < 16; off <<= 1)
                vmax = fmaxf(vmax, __shfl_xor(vmax, off));
            float ssum = 0.f;
#pragma unroll
            for (int ni = 0; ni < 4; ++ni) ssum += expf(vals[ni] - vmax);
#pragma unroll
            for (int off = 1; off < 16; off <<= 1) ssum += __shfl_xor(ssum, off);
            if (lane15 == 0) {
                int rl = wm * 64 + mi * 16 + quad * 4 + r;
                red[rl][wn] = make_float2(vmax, ssum);
            }
        }
    }
    __syncthreads();
    if (tid < 128) {
        float2 a = red[tid][0], b2 = red[tid][1];
        float M = fmaxf(a.x, b2.x);
        float S = a.y * expf(a.x - M) + b2.y * expf(b2.x - M);
        partials[(size_t)(mBase + tid) * NT_V + nT] = make_float2(M, S);
    }
}

// ---------------- persistent GRU ----------------
// 32 blocks, block blk owns h columns [blk*16, blk*16+16). W_hh slice bf16 in LDS.
// h exchanged via agent-scope relaxed atomic u64 (coherence point, no L2 fences).
// Barrier: per-block step-tagged flags, parallel poll, one acquire fence.
#define CRED(w,g,m,jc) Cred[(((w)*3+(g))*32+(m))*17+(jc)]

__global__ __launch_bounds__(256) void k_gru_persist(
    const float* __restrict__ W_hh, const float* __restrict__ gi,
    const float* __restrict__ b_hh, const float* __restrict__ h0,
    __bf16* __restrict__ Hbuf,   // [2][32][512] bf16 ping-pong
    __bf16* __restrict__ Hs,     // [MPAD][512] bf16
    float* __restrict__ Hfin,    // [32][512] fp32
    int* __restrict__ flags)     // [NBLK_GRU*FLAG_STRIDE]
{
    const int blk = blockIdx.x;
    const int j0 = blk * 16;
    const int tid = threadIdx.x;
    const int lane = tid & 63, wave = tid >> 6;
    const int lane15 = lane & 15, quad = lane >> 4;

    __shared__ __align__(16) __bf16 Wl[48 * 520];
    __shared__ float Cred[4 * 3 * 32 * 17];
    __shared__ __bf16 HbO[32][16];

    // load + convert W_hh slice: row rr=g*16+jc  <- W_hh[g*512 + j0 + jc][:]
    for (int idx = tid; idx < 48 * 128; idx += 256) {
        int rr = idx >> 7, k4 = (idx & 127) << 2;
        int g = rr >> 4, jc = rr & 15;
        float4 v = *(const float4*)(W_hh + (size_t)(g * 512 + j0 + jc) * 512 + k4);
        __bf16* d = &Wl[rr * 520 + k4];
        d[0] = (__bf16)v.x; d[1] = (__bf16)v.y; d[2] = (__bf16)v.z; d[3] = (__bf16)v.w;
    }

    const int m0 = tid >> 4, jc0 = tid & 15;   // unit 0: (m0,jc0); unit 1: (m0+16,jc0)
    const int m1 = m0 + 16;
    const float bhn = b_hh[1024 + j0 + jc0];
    const int k0 = wave * 128;                 // k-split across 4 waves
    float hp0 = h0[(size_t)m0 * HID + j0 + jc0];
    float hp1 = h0[(size_t)m1 * HID + j0 + jc0];

    // first step's gi
    float ir0, iz0, in0, ir1, iz1, in1;
    {
        const float* g0 = gi + (size_t)m0 * G3H + j0 + jc0;
        const float* g1 = gi + (size_t)m1 * G3H + j0 + jc0;
        ir0 = g0[0]; iz0 = g0[512]; in0 = g0[1024];
        ir1 = g1[0]; iz1 = g1[512]; in1 = g1[1024];
    }
    __syncthreads();

    for (int s = 0; s < NSTEP; ++s) {
        // ---- gather h_prev (all 32 rows x 128 k-slice) via agent-scope u64 loads ----
        const __bf16* hb = Hbuf + (size_t)(s & 1) * NB * HID;
        unsigned long long hq[2][4][2];
#pragma unroll
        for (int mt = 0; mt < 2; ++mt)
#pragma unroll
            for (int kk = 0; kk < 4; ++kk) {
                const unsigned long long* pp = (const unsigned long long*)
                    (hb + (size_t)(mt * 16 + lane15) * HID + k0 + kk * 32 + quad * 8);
                hq[mt][kk][0] = __hip_atomic_load(pp, __ATOMIC_RELAXED, __HIP_MEMORY_SCOPE_AGENT);
                hq[mt][kk][1] = __hip_atomic_load(pp + 1, __ATOMIC_RELAXED, __HIP_MEMORY_SCOPE_AGENT);
            }

        // ---- 3-gate MFMA, per-wave partials into Cred ----
        f32x4 acc[2][3];
        f32x4 zz = {0.f, 0.f, 0.f, 0.f};
#pragma unroll
        for (int mt = 0; mt < 2; ++mt)
#pragma unroll
            for (int g = 0; g < 3; ++g) acc[mt][g] = zz;
#pragma unroll
        for (int kk = 0; kk < 4; ++kk) {
            int ks = kk * 32;
            bf16x8 a0 = __builtin_bit_cast(bf16x8, u128{hq[0][kk][0], hq[0][kk][1]});
            bf16x8 a1 = __builtin_bit_cast(bf16x8, u128{hq[1][kk][0], hq[1][kk][1]});
#pragma unroll
            for (int g = 0; g < 3; ++g) {
                bf16x8 b4 = *(const bf16x8*)(&Wl[(g * 16 + lane15) * 520 + k0 + ks + quad * 8]);
                acc[0][g] = __builtin_amdgcn_mfma_f32_16x16x32_bf16(a0, b4, acc[0][g], 0, 0, 0);
                acc[1][g] = __builtin_amdgcn_mfma_f32_16x16x32_bf16(a1, b4, acc[1][g], 0, 0, 0);
            }
        }
#pragma unroll
        for (int mt = 0; mt < 2; ++mt)
#pragma unroll
            for (int g = 0; g < 3; ++g)
#pragma unroll
                for (int r = 0; r < 4; ++r)
                    CRED(wave, g, mt * 16 + quad * 4 + r, lane15) = acc[mt][g][r];
        __syncthreads();

        // ---- nonlinearity (fp32 h chain in registers) ----
        {
            float gr = CRED(0,0,m0,jc0) + CRED(1,0,m0,jc0) + CRED(2,0,m0,jc0) + CRED(3,0,m0,jc0);
            float gz = CRED(0,1,m0,jc0) + CRED(1,1,m0,jc0) + CRED(2,1,m0,jc0) + CRED(3,1,m0,jc0);
            float gn = CRED(0,2,m0,jc0) + CRED(1,2,m0,jc0) + CRED(2,2,m0,jc0) + CRED(3,2,m0,jc0);
            float r = 1.f / (1.f + expf(-(ir0 + gr)));
            float zg = 1.f / (1.f + expf(-(iz0 + gz)));
            float nn = tanhf(in0 + r * (gn + bhn));
            hp0 = (1.f - zg) * nn + zg * hp0;
            HbO[m0][jc0] = (__bf16)hp0;
        }
        {
            float gr = CRED(0,0,m1,jc0) + CRED(1,0,m1,jc0) + CRED(2,0,m1,jc0) + CRED(3,0,m1,jc0);
            float gz = CRED(0,1,m1,jc0) + CRED(1,1,m1,jc0) + CRED(2,1,m1,jc0) + CRED(3,1,m1,jc0);
            float gn = CRED(0,2,m1,jc0) + CRED(1,2,m1,jc0) + CRED(2,2,m1,jc0) + CRED(3,2,m1,jc0);
            float r = 1.f / (1.f + expf(-(ir1 + gr)));
            float zg = 1.f / (1.f + expf(-(iz1 + gz)));
            float nn = tanhf(in1 + r * (gn + bhn));
            hp1 = (1.f - zg) * nn + zg * hp1;
            HbO[m1][jc0] = (__bf16)hp1;
        }
        __syncthreads();

        // ---- publish own 16-col slice as packed u64 (agent scope) + Hs write ----
        if (tid < 128) {
            int m = tid >> 2, g4 = tid & 3;
            unsigned long long v0 = *(const unsigned short*)&HbO[m][g4 * 4 + 0];
            unsigned long long v1 = *(const unsigned short*)&HbO[m][g4 * 4 + 1];
            unsigned long long v2 = *(const unsigned short*)&HbO[m][g4 * 4 + 2];
            unsigned long long v3 = *(const unsigned short*)&HbO[m][g4 * 4 + 3];
            unsigned long long pk = v0 | (v1 << 16) | (v2 << 32) | (v3 << 48);
            unsigned long long* dst = (unsigned long long*)
                (Hbuf + (size_t)((s + 1) & 1) * NB * HID + (size_t)m * HID + j0 + g4 * 4);
            __hip_atomic_store(dst, pk, __ATOMIC_RELAXED, __HIP_MEMORY_SCOPE_AGENT);
            *(unsigned long long*)(Hs + (size_t)(s * NB + m) * HID + j0 + g4 * 4) = pk;
        }

        // prefetch next step's gi while waiting
        float nir0, niz0, nin0, nir1, niz1, nin1;
        if (s + 1 < NSTEP) {
            const float* g0 = gi + (size_t)((s + 1) * NB + m0) * G3H + j0 + jc0;
            const float* g1 = gi + (size_t)((s + 1) * NB + m1) * G3H + j0 + jc0;
            nir0 = g0[0]; niz0 = g0[512]; nin0 = g0[1024];
            nir1 = g1[0]; niz1 = g1[512]; nin1 = g1[1024];
        } else {
            nir0 = niz0 = nin0 = nir1 = niz1 = nin1 = 0.f;
        }
        __syncthreads();   // drains each wave's stores before arrival signal

        // ---- step barrier: per-block tagged flags, parallel poll ----
        if (tid == 0)
            __hip_atomic_store(&flags[blk * FLAG_STRIDE], s + 1,
                               __ATOMIC_RELEASE, __HIP_MEMORY_SCOPE_AGENT);
        if (tid < NBLK_GRU) {
            while (__hip_atomic_load(&flags[tid * FLAG_STRIDE],
                                     __ATOMIC_RELAXED, __HIP_MEMORY_SCOPE_AGENT) < s + 1)
                __builtin_amdgcn_s_sleep(1);
        }
        __builtin_amdgcn_fence(__ATOMIC_ACQUIRE, "agent");
        __syncthreads();

        ir0 = nir0; iz0 = niz0; in0 = nin0;
        ir1 = nir1; iz1 = niz1; in1 = nin1;
    }

    // final hidden state fp32
    Hfin[(size_t)m0 * HID + j0 + jc0] = hp0;
    Hfin[(size_t)m1 * HID + j0 + jc0] = hp1;
}

// ---------------- per-row log-likelihood ----------------
__global__ __launch_bounds__(128) void k_row_ll(const float2* __restrict__ partials,
                                                const __bf16* __restrict__ Hs,
                                                const __bf16* __restrict__ Wemb,
                                                const float* __restrict__ emit_b,
                                                const int* __restrict__ words,
                                                float* __restrict__ lls) {
    int s = blockIdx.x, n = blockIdx.y;
    int m = s * NB + n;
    int tid = threadIdx.x;
    int lane = tid & 63, w = tid >> 6;
    __shared__ float sm[2], ss[2], sd[2];
    const float2* prow = partials + (size_t)m * NT_V;
    float M = -__builtin_inff();
    for (int i = tid; i < NT_V; i += 128) M = fmaxf(M, prow[i].x);
#pragma unroll
    for (int off = 1; off < 64; off <<= 1) M = fmaxf(M, __shfl_xor(M, off));
    if (lane == 0) sm[w] = M;
    __syncthreads();
    M = fmaxf(sm[0], sm[1]);
    float S = 0.f;
    for (int i = tid; i < NT_V; i += 128) {
        float2 p = prow[i];
        S += p.y * expf(p.x - M);
    }
#pragma unroll
    for (int off = 1; off < 64; off <<= 1) S += __shfl_xor(S, off);
    if (lane == 0) ss[w] = S;
    __syncthreads();
    S = ss[0] + ss[1];
    int tw = words[n * TT + s + 1];
    float d = 0.f;
    const __bf16* hr = Hs + (size_t)m * HID;
    const __bf16* wr = Wemb + (size_t)tw * HID;
    for (int k = tid; k < HID; k += 128) d += (float)hr[k] * (float)wr[k];
#pragma unroll
    for (int off = 1; off < 64; off <<= 1) d += __shfl_xor(d, off);
    if (lane == 0) sd[w] = d;
    __syncthreads();
    if (tid == 0) {
        float dt = sd[0] + sd[1];
        lls[m] = dt + emit_b[tw] - (M + logf(S));
    }
}

// ---------------- final reduce ----------------
__global__ __launch_bounds__(128) void k_final(const float* __restrict__ lls,
                                               const float* __restrict__ Hfin,
                                               float* __restrict__ out) {
    int n = blockIdx.x;
    int tid = threadIdx.x;
    float s = 0.f;
    for (int i = tid; i < NSTEP; i += 128) s += lls[i * NB + n];
#pragma unroll
    for (int off = 1; off < 64; off <<= 1) s += __shfl_xor(s, off);
    __shared__ float t2[2];
    if ((tid & 63) == 0) t2[tid >> 6] = s;
    __syncthreads();
    if (tid == 0) out[n] = (t2[0] + t2[1]) / (float)NSTEP;
    for (int i = tid; i < HID; i += 128) out[NB + n * HID + i] = Hfin[(size_t)n * HID + i];
}

// ---------------- launch ----------------
extern "C" void kernel_launch(void* const* d_in, const int* in_sizes, int n_in,
                              void* d_out, int out_size, void* d_ws, size_t ws_size,
                              hipStream_t stream) {
    const int*   words   = (const int*)d_in[0];
    const float* hidden0 = (const float*)d_in[1];
    const float* embed_W = (const float*)d_in[2];
    const float* W_ih    = (const float*)d_in[3];
    const float* W_hh    = (const float*)d_in[4];
    const float* b_ih    = (const float*)d_in[5];
    const float* b_hh    = (const float*)d_in[6];
    const float* emit_W  = (const float*)d_in[7];
    const float* emit_b  = (const float*)d_in[8];
    float* out = (float*)d_out;

    char* p = (char*)d_ws;
    auto alloc = [&](size_t bytes) {
        void* r = (void*)p;
        p += (bytes + 255) & ~(size_t)255;
        return r;
    };
    __bf16* emit_Wb = (__bf16*)alloc((size_t)VPAD * 512 * 2);
    __bf16* Xb      = (__bf16*)alloc((size_t)MPAD * 512 * 2);
    __bf16* Wihb    = (__bf16*)alloc((size_t)G3H * 512 * 2);
    float*  gi      = (float*)alloc((size_t)MPAD * G3H * 4);
    __bf16* Hs      = (__bf16*)alloc((size_t)MPAD * 512 * 2);
    __bf16* Hbuf    = (__bf16*)alloc((size_t)2 * NB * HID * 2);
    float*  Hfin    = (float*)alloc((size_t)NB * HID * 4);
    float2* partials= (float2*)alloc((size_t)MPAD * NT_V * 8);
    float*  lls     = (float*)alloc((size_t)MROWS * 4);
    int*    flags   = (int*)alloc((size_t)NBLK_GRU * FLAG_STRIDE * 4);

    k_prep_emit<<<4096, 256, 0, stream>>>(emit_W, emit_Wb);
    k_prep_x<<<dim3(128, 32), 128, 0, stream>>>(words, embed_W, Xb, Hs);
    k_prep_wih<<<768, 256, 0, stream>>>(W_ih, Wihb);
    k_prep_h0<<<NB + 1, 256, 0, stream>>>(hidden0, Hbuf, flags);

    k_gemm_gi<<<dim3(32, 12), 256, 0, stream>>>(Xb, Wihb, b_ih, b_hh, gi);
    k_gru_persist<<<NBLK_GRU, 256, 0, stream>>>(W_hh, gi, b_hh, hidden0, Hbuf, Hs, Hfin, flags);

    k_gemm_emit<<<dim3(32, NT_V), 256, 0, stream>>>(Hs, emit_Wb, emit_b, partials);
    k_row_ll<<<dim3(NSTEP, 32), 128, 0, stream>>>(partials, Hs, emit_Wb, emit_b, words, lls);
    k_final<<<32, 128, 0, stream>>>(lls, Hfin, out);
}

// Round 4
// 1103.753 us; speedup vs baseline: 2.2046x; 1.2728x over previous
//
#include <hip/hip_runtime.h>
#include <math.h>

#define V_SIZE 50257
#define EMB 512
#define HID 512
#define NB 32
#define TT 128
#define NSTEP 127
#define G3H 1536
#define MROWS 4064   // NSTEP*NB
#define MPAD 4096
#define VPAD 50304   // 393*128
#define NT_V 393
#define NBLK_GRU 32
#define FLAG_STRIDE 32   // ints -> 128B per flag

typedef __attribute__((ext_vector_type(4))) float f32x4;
typedef __attribute__((ext_vector_type(8))) __bf16 bf16x8;
typedef __attribute__((ext_vector_type(4))) __bf16 bf16x4;

struct u128 { unsigned long long a, b; };

// async global->LDS, 16B per lane; LDS dst is wave-uniform base + lane*16
__device__ __forceinline__ void async16(const __bf16* g, __bf16* l) {
    __builtin_amdgcn_global_load_lds(
        (const __attribute__((address_space(1))) void*)g,
        (__attribute__((address_space(3))) void*)l, 16, 0, 0);
}

// ---------------- prep kernels ----------------

__global__ void k_prep_emit(const float* __restrict__ src, __bf16* __restrict__ dst) {
    size_t total4 = (size_t)VPAD * 512 / 4;
    size_t real4  = (size_t)V_SIZE * 512 / 4;
    for (size_t i4 = (size_t)blockIdx.x * blockDim.x + threadIdx.x; i4 < total4;
         i4 += (size_t)gridDim.x * blockDim.x) {
        float4 v = (i4 < real4) ? ((const float4*)src)[i4] : make_float4(0.f,0.f,0.f,0.f);
        bf16x4 o = {(__bf16)v.x, (__bf16)v.y, (__bf16)v.z, (__bf16)v.w};
        ((bf16x4*)dst)[i4] = o;
    }
}

__global__ void k_prep_wih(const float* __restrict__ src, __bf16* __restrict__ dst) {
    size_t total4 = (size_t)G3H * 512 / 4;
    for (size_t i4 = (size_t)blockIdx.x * blockDim.x + threadIdx.x; i4 < total4;
         i4 += (size_t)gridDim.x * blockDim.x) {
        float4 v = ((const float4*)src)[i4];
        bf16x4 o = {(__bf16)v.x, (__bf16)v.y, (__bf16)v.z, (__bf16)v.w};
        ((bf16x4*)dst)[i4] = o;
    }
}

// embedding gather -> Xb bf16 [MPAD,512]; zero pad rows of Xb and Hs
__global__ void k_prep_x(const int* __restrict__ words, const float* __restrict__ embed,
                         __bf16* __restrict__ Xb, __bf16* __restrict__ Hs) {
    int s = blockIdx.x;   // 0..127
    int n = blockIdx.y;   // 0..31
    int tid = threadIdx.x; // 128
    if (s < NSTEP) {
        int w = words[n * TT + s];
        size_t row = (size_t)(s * NB + n);
        const float4* src = (const float4*)(embed + (size_t)w * EMB);
        bf16x4* dst = (bf16x4*)(Xb + row * EMB);
        for (int c = tid; c < EMB / 4; c += 128) {
            float4 v = src[c];
            bf16x4 o = {(__bf16)v.x, (__bf16)v.y, (__bf16)v.z, (__bf16)v.w};
            dst[c] = o;
        }
    } else {
        size_t row = (size_t)(MROWS + n);
        bf16x4 z = {(__bf16)0.f, (__bf16)0.f, (__bf16)0.f, (__bf16)0.f};
        for (int c = tid; c < EMB / 4; c += 128) {
            ((bf16x4*)(Xb + row * EMB))[c] = z;
            ((bf16x4*)(Hs + row * HID))[c] = z;
        }
    }
}

// Hbuf[0] = bf16(h0); zero barrier flags
__global__ void k_prep_h0(const float* __restrict__ h0, __bf16* __restrict__ Hbuf,
                          int* __restrict__ flags) {
    int b = blockIdx.x;
    if (b < NB) {
        for (int k = threadIdx.x; k < HID; k += 256)
            Hbuf[b * HID + k] = (__bf16)h0[b * HID + k];
    } else {
        for (int k = threadIdx.x; k < NBLK_GRU * FLAG_STRIDE; k += 256) flags[k] = 0;
    }
}

// ---------------- 128x128 MFMA mainloop (used by gi GEMM) ----------------
// XOR-swizzled async16 staging: 16B chunk at physical slot ci holds logical
// chunk (ci ^ (row&7)) -> conflict-free ds_read_b128.

__device__ __forceinline__ void mm128(const __bf16* __restrict__ A,
                                      const __bf16* __restrict__ B,
                                      int mBase, int nBase, f32x4 acc[4][4],
                                      __bf16* As, __bf16* Bs) {
    const int tid = threadIdx.x;
    const int lane = tid & 63, wave = tid >> 6;
    const int wm = wave >> 1, wn = wave & 1;
    const int lane15 = lane & 15, quad = lane >> 4;
    for (int kc = 0; kc < 512; kc += 64) {
        __syncthreads();
#pragma unroll
        for (int i = 0; i < 4; ++i) {
            int c = (wave * 4 + i) * 64 + lane;   // 16B chunk id, 0..1023
            int row = c >> 3, ci = c & 7;
            int cis = ci ^ (row & 7);             // fetch swizzled source chunk
            async16(A + (size_t)(mBase + row) * 512 + kc + (cis << 3), As + (wave * 4 + i) * 512);
            async16(B + (size_t)(nBase + row) * 512 + kc + (cis << 3), Bs + (wave * 4 + i) * 512);
        }
        __syncthreads();
#pragma unroll
        for (int ks = 0; ks < 64; ks += 32) {
            bf16x8 a4[4], b4[4];
#pragma unroll
            for (int mi = 0; mi < 4; ++mi) {
                int row = wm * 64 + mi * 16 + lane15;
                int L = (ks >> 3) + quad;
                a4[mi] = *(const bf16x8*)(As + row * 64 + ((L ^ (row & 7)) << 3));
            }
#pragma unroll
            for (int ni = 0; ni < 4; ++ni) {
                int row = wn * 64 + ni * 16 + lane15;
                int L = (ks >> 3) + quad;
                b4[ni] = *(const bf16x8*)(Bs + row * 64 + ((L ^ (row & 7)) << 3));
            }
#pragma unroll
            for (int mi = 0; mi < 4; ++mi)
#pragma unroll
                for (int ni = 0; ni < 4; ++ni)
                    acc[mi][ni] = __builtin_amdgcn_mfma_f32_16x16x32_bf16(
                        a4[mi], b4[ni], acc[mi][ni], 0, 0, 0);
        }
    }
}

// gi = Xb @ W_ih^T + b_ih (+ b_hh for r,z gates)  -> fp32 [MPAD][1536]
__global__ __launch_bounds__(256) void k_gemm_gi(const __bf16* __restrict__ Xb,
                                                 const __bf16* __restrict__ Wihb,
                                                 const float* __restrict__ b_ih,
                                                 const float* __restrict__ b_hh,
                                                 float* __restrict__ gi) {
    __shared__ __align__(16) __bf16 As[128 * 64];
    __shared__ __align__(16) __bf16 Bs[128 * 64];
    f32x4 acc[4][4];
    f32x4 z = {0.f, 0.f, 0.f, 0.f};
#pragma unroll
    for (int mi = 0; mi < 4; ++mi)
#pragma unroll
        for (int ni = 0; ni < 4; ++ni) acc[mi][ni] = z;
    int mBase = blockIdx.x * 128, nBase = blockIdx.y * 128;
    mm128(Xb, Wihb, mBase, nBase, acc, As, Bs);
    const int tid = threadIdx.x, lane = tid & 63, wave = tid >> 6;
    const int wm = wave >> 1, wn = wave & 1, lane15 = lane & 15, quad = lane >> 4;
#pragma unroll
    for (int ni = 0; ni < 4; ++ni) {
        int col = nBase + wn * 64 + ni * 16 + lane15;
        float bias = b_ih[col] + (col < 1024 ? b_hh[col] : 0.0f);
#pragma unroll
        for (int mi = 0; mi < 4; ++mi) {
            int rowb = wm * 64 + mi * 16 + quad * 4;
#pragma unroll
            for (int r = 0; r < 4; ++r) {
                int m = mBase + rowb + r;
                gi[(size_t)m * G3H + col] = acc[mi][ni][r] + bias;
            }
        }
    }
}

// ---------------- emit GEMM, 256x128 tile, fused logsumexp partials ----------------
// Wave w owns rows [mBase+w*64, +64) x all 128 cols -> logsumexp reduce is
// fully in-wave (8 ni regs + shfl over 16 lanes), no LDS combine.
__global__ __launch_bounds__(256, 2) void k_gemm_emit(const __bf16* __restrict__ Hs,
                                                      const __bf16* __restrict__ Wemb,
                                                      const float* __restrict__ emit_b,
                                                      float2* __restrict__ partials) {
    __shared__ __align__(16) __bf16 As[256 * 64];   // 32 KB
    __shared__ __align__(16) __bf16 Bs[128 * 64];   // 16 KB
    f32x4 acc[4][8];
    f32x4 z = {0.f, 0.f, 0.f, 0.f};
#pragma unroll
    for (int mi = 0; mi < 4; ++mi)
#pragma unroll
        for (int ni = 0; ni < 8; ++ni) acc[mi][ni] = z;
    const int mBase = blockIdx.x * 256;
    const int nT = blockIdx.y, nBase = nT * 128;
    const int tid = threadIdx.x, lane = tid & 63, wave = tid >> 6;
    const int lane15 = lane & 15, quad = lane >> 4;

    for (int kc = 0; kc < 512; kc += 64) {
        __syncthreads();
#pragma unroll
        for (int i = 0; i < 8; ++i) {
            int c = (wave * 8 + i) * 64 + lane;   // 0..2047
            int row = c >> 3, ci = c & 7;
            int cis = ci ^ (row & 7);
            async16(Hs + (size_t)(mBase + row) * 512 + kc + (cis << 3), As + (wave * 8 + i) * 512);
        }
#pragma unroll
        for (int i = 0; i < 4; ++i) {
            int c = (wave * 4 + i) * 64 + lane;   // 0..1023
            int row = c >> 3, ci = c & 7;
            int cis = ci ^ (row & 7);
            async16(Wemb + (size_t)(nBase + row) * 512 + kc + (cis << 3), Bs + (wave * 4 + i) * 512);
        }
        __syncthreads();
#pragma unroll
        for (int ks = 0; ks < 64; ks += 32) {
            int L = (ks >> 3) + quad;
            bf16x8 a4[4], b4[8];
#pragma unroll
            for (int mi = 0; mi < 4; ++mi) {
                int row = wave * 64 + mi * 16 + lane15;
                a4[mi] = *(const bf16x8*)(As + row * 64 + ((L ^ (row & 7)) << 3));
            }
#pragma unroll
            for (int ni = 0; ni < 8; ++ni) {
                int row = ni * 16 + lane15;
                b4[ni] = *(const bf16x8*)(Bs + row * 64 + ((L ^ (row & 7)) << 3));
            }
#pragma unroll
            for (int mi = 0; mi < 4; ++mi)
#pragma unroll
                for (int ni = 0; ni < 8; ++ni)
                    acc[mi][ni] = __builtin_amdgcn_mfma_f32_16x16x32_bf16(
                        a4[mi], b4[ni], acc[mi][ni], 0, 0, 0);
        }
    }

    const float NINF = -__builtin_inff();
    float bv[8];
    bool valid[8];
#pragma unroll
    for (int ni = 0; ni < 8; ++ni) {
        int col = nBase + ni * 16 + lane15;
        valid[ni] = (col < V_SIZE);
        bv[ni] = valid[ni] ? emit_b[col] : 0.0f;
    }
#pragma unroll
    for (int mi = 0; mi < 4; ++mi) {
#pragma unroll
        for (int r = 0; r < 4; ++r) {
            float vals[8];
            float vmax = NINF;
#pragma unroll
            for (int ni = 0; ni < 8; ++ni) {
                float v = acc[mi][ni][r] + bv[ni];
                if (!valid[ni]) v = NINF;
                vals[ni] = v;
                vmax = fmaxf(vmax, v);
            }
#pragma unroll
            for (int off = 1; off < 16; off <<= 1)
                vmax = fmaxf(vmax, __shfl_xor(vmax, off));
            float ssum = 0.f;
#pragma unroll
            for (int ni = 0; ni < 8; ++ni) ssum += expf(vals[ni] - vmax);
#pragma unroll
            for (int off = 1; off < 16; off <<= 1) ssum += __shfl_xor(ssum, off);
            if (lane15 == 0) {
                int m = mBase + wave * 64 + mi * 16 + quad * 4 + r;
                partials[(size_t)m * NT_V + nT] = make_float2(vmax, ssum);
            }
        }
    }
}

// ---------------- persistent GRU ----------------
// 32 blocks, block blk owns h columns [blk*16, blk*16+16). W_hh slice bf16 in LDS.
// All cross-block data (Hbuf, flags) moves via sc1 (agent-relaxed atomic) ops ->
// straight to LLC; ordering is s_waitcnt vmcnt(0) before flag store. NO L2
// writeback/invalidate fences (the r3 release/acquire fences cost ~4 us/step).
#define CRED(w,g,m,jc) Cred[(((w)*3+(g))*32+(m))*17+(jc)]

__global__ __launch_bounds__(256) void k_gru_persist(
    const float* __restrict__ W_hh, const float* __restrict__ gi,
    const float* __restrict__ b_hh, const float* __restrict__ h0,
    __bf16* __restrict__ Hbuf,   // [2][32][512] bf16 ping-pong
    __bf16* __restrict__ Hs,     // [MPAD][512] bf16
    float* __restrict__ Hfin,    // [32][512] fp32
    int* __restrict__ flags)     // [NBLK_GRU*FLAG_STRIDE]
{
    const int blk = blockIdx.x;
    const int j0 = blk * 16;
    const int tid = threadIdx.x;
    const int lane = tid & 63, wave = tid >> 6;
    const int lane15 = lane & 15, quad = lane >> 4;

    __shared__ __align__(16) __bf16 Wl[48 * 520];
    __shared__ float Cred[4 * 3 * 32 * 17];
    __shared__ __bf16 HbO[32][16];

    // load + convert W_hh slice: row rr=g*16+jc  <- W_hh[g*512 + j0 + jc][:]
    for (int idx = tid; idx < 48 * 128; idx += 256) {
        int rr = idx >> 7, k4 = (idx & 127) << 2;
        int g = rr >> 4, jc = rr & 15;
        float4 v = *(const float4*)(W_hh + (size_t)(g * 512 + j0 + jc) * 512 + k4);
        __bf16* d = &Wl[rr * 520 + k4];
        d[0] = (__bf16)v.x; d[1] = (__bf16)v.y; d[2] = (__bf16)v.z; d[3] = (__bf16)v.w;
    }

    const int m0 = tid >> 4, jc0 = tid & 15;   // unit 0: (m0,jc0); unit 1: (m0+16,jc0)
    const int m1 = m0 + 16;
    const float bhn = b_hh[1024 + j0 + jc0];
    const int k0 = wave * 128;                 // k-split across 4 waves
    float hp0 = h0[(size_t)m0 * HID + j0 + jc0];
    float hp1 = h0[(size_t)m1 * HID + j0 + jc0];

    // first step's gi
    float ir0, iz0, in0, ir1, iz1, in1;
    {
        const float* g0 = gi + (size_t)m0 * G3H + j0 + jc0;
        const float* g1 = gi + (size_t)m1 * G3H + j0 + jc0;
        ir0 = g0[0]; iz0 = g0[512]; in0 = g0[1024];
        ir1 = g1[0]; iz1 = g1[512]; in1 = g1[1024];
    }
    __syncthreads();

    for (int s = 0; s < NSTEP; ++s) {
        // ---- gather h_prev (all 32 rows x 128 k-slice) via sc1 u64 loads ----
        const __bf16* hb = Hbuf + (size_t)(s & 1) * NB * HID;
        unsigned long long hq[2][4][2];
#pragma unroll
        for (int mt = 0; mt < 2; ++mt)
#pragma unroll
            for (int kk = 0; kk < 4; ++kk) {
                const unsigned long long* pp = (const unsigned long long*)
                    (hb + (size_t)(mt * 16 + lane15) * HID + k0 + kk * 32 + quad * 8);
                hq[mt][kk][0] = __hip_atomic_load(pp, __ATOMIC_RELAXED, __HIP_MEMORY_SCOPE_AGENT);
                hq[mt][kk][1] = __hip_atomic_load(pp + 1, __ATOMIC_RELAXED, __HIP_MEMORY_SCOPE_AGENT);
            }

        // ---- 3-gate MFMA, per-wave partials into Cred ----
        f32x4 acc[2][3];
        f32x4 zz = {0.f, 0.f, 0.f, 0.f};
#pragma unroll
        for (int mt = 0; mt < 2; ++mt)
#pragma unroll
            for (int g = 0; g < 3; ++g) acc[mt][g] = zz;
#pragma unroll
        for (int kk = 0; kk < 4; ++kk) {
            int ks = kk * 32;
            bf16x8 a0 = __builtin_bit_cast(bf16x8, u128{hq[0][kk][0], hq[0][kk][1]});
            bf16x8 a1 = __builtin_bit_cast(bf16x8, u128{hq[1][kk][0], hq[1][kk][1]});
#pragma unroll
            for (int g = 0; g < 3; ++g) {
                bf16x8 b4 = *(const bf16x8*)(&Wl[(g * 16 + lane15) * 520 + k0 + ks + quad * 8]);
                acc[0][g] = __builtin_amdgcn_mfma_f32_16x16x32_bf16(a0, b4, acc[0][g], 0, 0, 0);
                acc[1][g] = __builtin_amdgcn_mfma_f32_16x16x32_bf16(a1, b4, acc[1][g], 0, 0, 0);
            }
        }
#pragma unroll
        for (int mt = 0; mt < 2; ++mt)
#pragma unroll
            for (int g = 0; g < 3; ++g)
#pragma unroll
                for (int r = 0; r < 4; ++r)
                    CRED(wave, g, mt * 16 + quad * 4 + r, lane15) = acc[mt][g][r];
        __syncthreads();

        // ---- nonlinearity (fp32 h chain in registers) ----
        {
            float gr = CRED(0,0,m0,jc0) + CRED(1,0,m0,jc0) + CRED(2,0,m0,jc0) + CRED(3,0,m0,jc0);
            float gz = CRED(0,1,m0,jc0) + CRED(1,1,m0,jc0) + CRED(2,1,m0,jc0) + CRED(3,1,m0,jc0);
            float gn = CRED(0,2,m0,jc0) + CRED(1,2,m0,jc0) + CRED(2,2,m0,jc0) + CRED(3,2,m0,jc0);
            float r = 1.f / (1.f + expf(-(ir0 + gr)));
            float zg = 1.f / (1.f + expf(-(iz0 + gz)));
            float nn = tanhf(in0 + r * (gn + bhn));
            hp0 = (1.f - zg) * nn + zg * hp0;
            HbO[m0][jc0] = (__bf16)hp0;
        }
        {
            float gr = CRED(0,0,m1,jc0) + CRED(1,0,m1,jc0) + CRED(2,0,m1,jc0) + CRED(3,0,m1,jc0);
            float gz = CRED(0,1,m1,jc0) + CRED(1,1,m1,jc0) + CRED(2,1,m1,jc0) + CRED(3,1,m1,jc0);
            float gn = CRED(0,2,m1,jc0) + CRED(1,2,m1,jc0) + CRED(2,2,m1,jc0) + CRED(3,2,m1,jc0);
            float r = 1.f / (1.f + expf(-(ir1 + gr)));
            float zg = 1.f / (1.f + expf(-(iz1 + gz)));
            float nn = tanhf(in1 + r * (gn + bhn));
            hp1 = (1.f - zg) * nn + zg * hp1;
            HbO[m1][jc0] = (__bf16)hp1;
        }
        __syncthreads();

        // ---- publish own 16-col slice as packed u64 (sc1) + Hs write ----
        if (tid < 128) {
            int m = tid >> 2, g4 = tid & 3;
            unsigned long long v0 = *(const unsigned short*)&HbO[m][g4 * 4 + 0];
            unsigned long long v1 = *(const unsigned short*)&HbO[m][g4 * 4 + 1];
            unsigned long long v2 = *(const unsigned short*)&HbO[m][g4 * 4 + 2];
            unsigned long long v3 = *(const unsigned short*)&HbO[m][g4 * 4 + 3];
            unsigned long long pk = v0 | (v1 << 16) | (v2 << 32) | (v3 << 48);
            unsigned long long* dst = (unsigned long long*)
                (Hbuf + (size_t)((s + 1) & 1) * NB * HID + (size_t)m * HID + j0 + g4 * 4);
            __hip_atomic_store(dst, pk, __ATOMIC_RELAXED, __HIP_MEMORY_SCOPE_AGENT);
            *(unsigned long long*)(Hs + (size_t)(s * NB + m) * HID + j0 + g4 * 4) = pk;
        }

        // prefetch next step's gi while waiting
        float nir0, niz0, nin0, nir1, niz1, nin1;
        if (s + 1 < NSTEP) {
            const float* g0 = gi + (size_t)((s + 1) * NB + m0) * G3H + j0 + jc0;
            const float* g1 = gi + (size_t)((s + 1) * NB + m1) * G3H + j0 + jc0;
            nir0 = g0[0]; niz0 = g0[512]; nin0 = g0[1024];
            nir1 = g1[0]; niz1 = g1[512]; nin1 = g1[1024];
        } else {
            nir0 = niz0 = nin0 = nir1 = niz1 = nin1 = 0.f;
        }

        // drain own sc1 publish stores (vmcnt(0); expcnt/lgkmcnt masked off)
        __builtin_amdgcn_s_waitcnt(0x0f70);
        __syncthreads();   // all waves' publishes drained before flag store

        // ---- step barrier: per-block tagged flags (sc1), parallel poll ----
        if (tid == 0)
            __hip_atomic_store(&flags[blk * FLAG_STRIDE], s + 1,
                               __ATOMIC_RELAXED, __HIP_MEMORY_SCOPE_AGENT);
        if (tid < NBLK_GRU) {
            while (__hip_atomic_load(&flags[tid * FLAG_STRIDE],
                                     __ATOMIC_RELAXED, __HIP_MEMORY_SCOPE_AGENT) < s + 1)
                __builtin_amdgcn_s_sleep(1);
        }
        __syncthreads();   // orders next iteration's sc1 h loads after the poll

        ir0 = nir0; iz0 = niz0; in0 = nin0;
        ir1 = nir1; iz1 = niz1; in1 = nin1;
    }

    // final hidden state fp32
    Hfin[(size_t)m0 * HID + j0 + jc0] = hp0;
    Hfin[(size_t)m1 * HID + j0 + jc0] = hp1;
}

// ---------------- per-row log-likelihood ----------------
__global__ __launch_bounds__(128) void k_row_ll(const float2* __restrict__ partials,
                                                const __bf16* __restrict__ Hs,
                                                const __bf16* __restrict__ Wemb,
                                                const float* __restrict__ emit_b,
                                                const int* __restrict__ words,
                                                float* __restrict__ lls) {
    int s = blockIdx.x, n = blockIdx.y;
    int m = s * NB + n;
    int tid = threadIdx.x;
    int lane = tid & 63, w = tid >> 6;
    __shared__ float sm[2], ss[2], sd[2];
    const float2* prow = partials + (size_t)m * NT_V;
    float M = -__builtin_inff();
    for (int i = tid; i < NT_V; i += 128) M = fmaxf(M, prow[i].x);
#pragma unroll
    for (int off = 1; off < 64; off <<= 1) M = fmaxf(M, __shfl_xor(M, off));
    if (lane == 0) sm[w] = M;
    __syncthreads();
    M = fmaxf(sm[0], sm[1]);
    float S = 0.f;
    for (int i = tid; i < NT_V; i += 128) {
        float2 p = prow[i];
        S += p.y * expf(p.x - M);
    }
#pragma unroll
    for (int off = 1; off < 64; off <<= 1) S += __shfl_xor(S, off);
    if (lane == 0) ss[w] = S;
    __syncthreads();
    S = ss[0] + ss[1];
    int tw = words[n * TT + s + 1];
    float d = 0.f;
    const __bf16* hr = Hs + (size_t)m * HID;
    const __bf16* wr = Wemb + (size_t)tw * HID;
    for (int k = tid; k < HID; k += 128) d += (float)hr[k] * (float)wr[k];
#pragma unroll
    for (int off = 1; off < 64; off <<= 1) d += __shfl_xor(d, off);
    if (lane == 0) sd[w] = d;
    __syncthreads();
    if (tid == 0) {
        float dt = sd[0] + sd[1];
        lls[m] = dt + emit_b[tw] - (M + logf(S));
    }
}

// ---------------- final reduce ----------------
__global__ __launch_bounds__(128) void k_final(const float* __restrict__ lls,
                                               const float* __restrict__ Hfin,
                                               float* __restrict__ out) {
    int n = blockIdx.x;
    int tid = threadIdx.x;
    float s = 0.f;
    for (int i = tid; i < NSTEP; i += 128) s += lls[i * NB + n];
#pragma unroll
    for (int off = 1; off < 64; off <<= 1) s += __shfl_xor(s, off);
    __shared__ float t2[2];
    if ((tid & 63) == 0) t2[tid >> 6] = s;
    __syncthreads();
    if (tid == 0) out[n] = (t2[0] + t2[1]) / (float)NSTEP;
    for (int i = tid; i < HID; i += 128) out[NB + n * HID + i] = Hfin[(size_t)n * HID + i];
}

// ---------------- launch ----------------
extern "C" void kernel_launch(void* const* d_in, const int* in_sizes, int n_in,
                              void* d_out, int out_size, void* d_ws, size_t ws_size,
                              hipStream_t stream) {
    const int*   words   = (const int*)d_in[0];
    const float* hidden0 = (const float*)d_in[1];
    const float* embed_W = (const float*)d_in[2];
    const float* W_ih    = (const float*)d_in[3];
    const float* W_hh    = (const float*)d_in[4];
    const float* b_ih    = (const float*)d_in[5];
    const float* b_hh    = (const float*)d_in[6];
    const float* emit_W  = (const float*)d_in[7];
    const float* emit_b  = (const float*)d_in[8];
    float* out = (float*)d_out;

    char* p = (char*)d_ws;
    auto alloc = [&](size_t bytes) {
        void* r = (void*)p;
        p += (bytes + 255) & ~(size_t)255;
        return r;
    };
    __bf16* emit_Wb = (__bf16*)alloc((size_t)VPAD * 512 * 2);
    __bf16* Xb      = (__bf16*)alloc((size_t)MPAD * 512 * 2);
    __bf16* Wihb    = (__bf16*)alloc((size_t)G3H * 512 * 2);
    float*  gi      = (float*)alloc((size_t)MPAD * G3H * 4);
    __bf16* Hs      = (__bf16*)alloc((size_t)MPAD * 512 * 2);
    __bf16* Hbuf    = (__bf16*)alloc((size_t)2 * NB * HID * 2);
    float*  Hfin    = (float*)alloc((size_t)NB * HID * 4);
    float2* partials= (float2*)alloc((size_t)MPAD * NT_V * 8);
    float*  lls     = (float*)alloc((size_t)MROWS * 4);
    int*    flags   = (int*)alloc((size_t)NBLK_GRU * FLAG_STRIDE * 4);

    k_prep_emit<<<4096, 256, 0, stream>>>(emit_W, emit_Wb);
    k_prep_x<<<dim3(128, 32), 128, 0, stream>>>(words, embed_W, Xb, Hs);
    k_prep_wih<<<768, 256, 0, stream>>>(W_ih, Wihb);
    k_prep_h0<<<NB + 1, 256, 0, stream>>>(hidden0, Hbuf, flags);

    k_gemm_gi<<<dim3(32, 12), 256, 0, stream>>>(Xb, Wihb, b_ih, b_hh, gi);
    k_gru_persist<<<NBLK_GRU, 256, 0, stream>>>(W_hh, gi, b_hh, hidden0, Hbuf, Hs, Hfin, flags);

    k_gemm_emit<<<dim3(16, NT_V), 256, 0, stream>>>(Hs, emit_Wb, emit_b, partials);
    k_row_ll<<<dim3(NSTEP, 32), 128, 0, stream>>>(partials, Hs, emit_Wb, emit_b, words, lls);
    k_final<<<32, 128, 0, stream>>>(lls, Hfin, out);
}

// Round 5
// 878.838 us; speedup vs baseline: 2.7688x; 1.2559x over previous
//
#include <hip/hip_runtime.h>
#include <math.h>

#define V_SIZE 50257
#define EMB 512
#define HID 512
#define NB 32
#define TT 128
#define NSTEP 127
#define G3H 1536
#define MROWS 4064   // NSTEP*NB
#define MPAD 4096
#define VPAD 50304   // 393*128
#define NT_V 393
#define NBLK_GRU 32
#define FLAG_STRIDE 32    // ints -> 128B per flag
#define NTILE (16 * NT_V) // 16 m-chunks of 256 rows x 393 col-tiles
#define NWORKER 448
#define SMEM_BYTES 77312

typedef __attribute__((ext_vector_type(4))) float f32x4;
typedef __attribute__((ext_vector_type(8))) __bf16 bf16x8;
typedef __attribute__((ext_vector_type(4))) __bf16 bf16x4;

struct u128 { unsigned long long a, b; };

// async global->LDS, 16B per lane; LDS dst is wave-uniform base + lane*16
__device__ __forceinline__ void async16(const __bf16* g, __bf16* l) {
    __builtin_amdgcn_global_load_lds(
        (const __attribute__((address_space(1))) void*)g,
        (__attribute__((address_space(3))) void*)l, 16, 0, 0);
}

// ---------------- prep kernels ----------------

__global__ void k_prep_emit(const float* __restrict__ src, __bf16* __restrict__ dst) {
    size_t total4 = (size_t)VPAD * 512 / 4;
    size_t real4  = (size_t)V_SIZE * 512 / 4;
    for (size_t i4 = (size_t)blockIdx.x * blockDim.x + threadIdx.x; i4 < total4;
         i4 += (size_t)gridDim.x * blockDim.x) {
        float4 v = (i4 < real4) ? ((const float4*)src)[i4] : make_float4(0.f,0.f,0.f,0.f);
        bf16x4 o = {(__bf16)v.x, (__bf16)v.y, (__bf16)v.z, (__bf16)v.w};
        ((bf16x4*)dst)[i4] = o;
    }
}

__global__ void k_prep_wih(const float* __restrict__ src, __bf16* __restrict__ dst) {
    size_t total4 = (size_t)G3H * 512 / 4;
    for (size_t i4 = (size_t)blockIdx.x * blockDim.x + threadIdx.x; i4 < total4;
         i4 += (size_t)gridDim.x * blockDim.x) {
        float4 v = ((const float4*)src)[i4];
        bf16x4 o = {(__bf16)v.x, (__bf16)v.y, (__bf16)v.z, (__bf16)v.w};
        ((bf16x4*)dst)[i4] = o;
    }
}

// embedding gather -> Xb bf16 [MPAD,512]; zero pad rows of Xb and Hs
__global__ void k_prep_x(const int* __restrict__ words, const float* __restrict__ embed,
                         __bf16* __restrict__ Xb, __bf16* __restrict__ Hs) {
    int s = blockIdx.x;   // 0..127
    int n = blockIdx.y;   // 0..31
    int tid = threadIdx.x; // 128
    if (s < NSTEP) {
        int w = words[n * TT + s];
        size_t row = (size_t)(s * NB + n);
        const float4* src = (const float4*)(embed + (size_t)w * EMB);
        bf16x4* dst = (bf16x4*)(Xb + row * EMB);
        for (int c = tid; c < EMB / 4; c += 128) {
            float4 v = src[c];
            bf16x4 o = {(__bf16)v.x, (__bf16)v.y, (__bf16)v.z, (__bf16)v.w};
            dst[c] = o;
        }
    } else {
        size_t row = (size_t)(MROWS + n);
        bf16x4 z = {(__bf16)0.f, (__bf16)0.f, (__bf16)0.f, (__bf16)0.f};
        for (int c = tid; c < EMB / 4; c += 128) {
            ((bf16x4*)(Xb + row * EMB))[c] = z;
            ((bf16x4*)(Hs + row * HID))[c] = z;
        }
    }
}

// Hbuf[0] = bf16(h0); zero control block (ticket/progress/flags)
__global__ void k_prep_h0(const float* __restrict__ h0, __bf16* __restrict__ Hbuf,
                          int* __restrict__ ctrl) {
    int b = blockIdx.x;
    if (b < NB) {
        for (int k = threadIdx.x; k < HID; k += 256)
            Hbuf[b * HID + k] = (__bf16)h0[b * HID + k];
    } else {
        for (int k = threadIdx.x; k < 2048; k += 256) ctrl[k] = 0;
    }
}

// ---------------- 128x128 MFMA mainloop (gi GEMM) ----------------
// XOR-swizzled async16 staging: 16B chunk at physical slot ci holds logical
// chunk (ci ^ (row&7)) -> conflict-free ds_read_b128.

__device__ __forceinline__ void mm128(const __bf16* __restrict__ A,
                                      const __bf16* __restrict__ B,
                                      int mBase, int nBase, f32x4 acc[4][4],
                                      __bf16* As, __bf16* Bs) {
    const int tid = threadIdx.x;
    const int lane = tid & 63, wave = tid >> 6;
    const int wm = wave >> 1, wn = wave & 1;
    const int lane15 = lane & 15, quad = lane >> 4;
    for (int kc = 0; kc < 512; kc += 64) {
        __syncthreads();
#pragma unroll
        for (int i = 0; i < 4; ++i) {
            int c = (wave * 4 + i) * 64 + lane;   // 16B chunk id, 0..1023
            int row = c >> 3, ci = c & 7;
            int cis = ci ^ (row & 7);
            async16(A + (size_t)(mBase + row) * 512 + kc + (cis << 3), As + (wave * 4 + i) * 512);
            async16(B + (size_t)(nBase + row) * 512 + kc + (cis << 3), Bs + (wave * 4 + i) * 512);
        }
        __syncthreads();
#pragma unroll
        for (int ks = 0; ks < 64; ks += 32) {
            bf16x8 a4[4], b4[4];
#pragma unroll
            for (int mi = 0; mi < 4; ++mi) {
                int row = wm * 64 + mi * 16 + lane15;
                int L = (ks >> 3) + quad;
                a4[mi] = *(const bf16x8*)(As + row * 64 + ((L ^ (row & 7)) << 3));
            }
#pragma unroll
            for (int ni = 0; ni < 4; ++ni) {
                int row = wn * 64 + ni * 16 + lane15;
                int L = (ks >> 3) + quad;
                b4[ni] = *(const bf16x8*)(Bs + row * 64 + ((L ^ (row & 7)) << 3));
            }
#pragma unroll
            for (int mi = 0; mi < 4; ++mi)
#pragma unroll
                for (int ni = 0; ni < 4; ++ni)
                    acc[mi][ni] = __builtin_amdgcn_mfma_f32_16x16x32_bf16(
                        a4[mi], b4[ni], acc[mi][ni], 0, 0, 0);
        }
    }
}

// gi = Xb @ W_ih^T + b_ih (+ b_hh for r,z gates)  -> fp32 [MPAD][1536]
__global__ __launch_bounds__(256) void k_gemm_gi(const __bf16* __restrict__ Xb,
                                                 const __bf16* __restrict__ Wihb,
                                                 const float* __restrict__ b_ih,
                                                 const float* __restrict__ b_hh,
                                                 float* __restrict__ gi) {
    __shared__ __align__(16) __bf16 As[128 * 64];
    __shared__ __align__(16) __bf16 Bs[128 * 64];
    f32x4 acc[4][4];
    f32x4 z = {0.f, 0.f, 0.f, 0.f};
#pragma unroll
    for (int mi = 0; mi < 4; ++mi)
#pragma unroll
        for (int ni = 0; ni < 4; ++ni) acc[mi][ni] = z;
    int mBase = blockIdx.x * 128, nBase = blockIdx.y * 128;
    mm128(Xb, Wihb, mBase, nBase, acc, As, Bs);
    const int tid = threadIdx.x, lane = tid & 63, wave = tid >> 6;
    const int wm = wave >> 1, wn = wave & 1, lane15 = lane & 15, quad = lane >> 4;
#pragma unroll
    for (int ni = 0; ni < 4; ++ni) {
        int col = nBase + wn * 64 + ni * 16 + lane15;
        float bias = b_ih[col] + (col < 1024 ? b_hh[col] : 0.0f);
#pragma unroll
        for (int mi = 0; mi < 4; ++mi) {
            int rowb = wm * 64 + mi * 16 + quad * 4;
#pragma unroll
            for (int r = 0; r < 4; ++r) {
                int m = mBase + rowb + r;
                gi[(size_t)m * G3H + col] = acc[mi][ni][r] + bias;
            }
        }
    }
}

// ---------------- fused persistent kernel: GRU producers + emit workers ----------------
// blocks 0..31: GRU (block blk owns h cols [blk*16,+16)); publish Hbuf/Hs sc1,
//   step barrier via tagged flags, block 0 publishes progress counter.
// blocks 32..: persistent emit workers; pull 256x128 tiles via sc1 ticket,
//   gate on progress >= steps covered by the tile's row chunk.
#define CREDp(w,g,m,jc) Cred[(((w)*3+(g))*32+(m))*17+(jc)]

__global__ __launch_bounds__(256, 2) void k_fused(
    const float* __restrict__ W_hh, const float* __restrict__ gi,
    const float* __restrict__ b_hh, const float* __restrict__ h0,
    __bf16* __restrict__ Hbuf,   // [2][32][512] bf16 ping-pong
    __bf16* __restrict__ Hs,     // [MPAD][512] bf16 (sc1-published)
    float* __restrict__ Hfin,    // [32][512] fp32
    const __bf16* __restrict__ Wemb,
    const float* __restrict__ emit_b,
    float2* __restrict__ partials,
    int* __restrict__ ctrl)      // [0]=ticket, [32]=progress, [64+blk*32]=flags
{
    __shared__ __align__(16) char smem[SMEM_BYTES];
    __shared__ int tShare;
    const int tid = threadIdx.x;
    const int lane = tid & 63, wave = tid >> 6;
    const int lane15 = lane & 15, quad = lane >> 4;
    int* ticket   = ctrl;
    int* progress = ctrl + 32;
    int* flags    = ctrl + 64;

    if (blockIdx.x < NBLK_GRU) {
        // ================= GRU producer =================
        const int blk = blockIdx.x;
        const int j0 = blk * 16;
        __bf16* Wl  = (__bf16*)smem;                    // 48*520*2 = 49920
        float* Cred = (float*)(smem + 49920);           // 4*3*32*17*4 = 26112
        __bf16 (*HbO)[16] = (__bf16(*)[16])(smem + 76032); // 1024

        for (int idx = tid; idx < 48 * 128; idx += 256) {
            int rr = idx >> 7, k4 = (idx & 127) << 2;
            int g = rr >> 4, jc = rr & 15;
            float4 v = *(const float4*)(W_hh + (size_t)(g * 512 + j0 + jc) * 512 + k4);
            __bf16* d = &Wl[rr * 520 + k4];
            d[0] = (__bf16)v.x; d[1] = (__bf16)v.y; d[2] = (__bf16)v.z; d[3] = (__bf16)v.w;
        }

        const int m0 = tid >> 4, jc0 = tid & 15;
        const int m1 = m0 + 16;
        const float bhn = b_hh[1024 + j0 + jc0];
        const int k0 = wave * 128;
        float hp0 = h0[(size_t)m0 * HID + j0 + jc0];
        float hp1 = h0[(size_t)m1 * HID + j0 + jc0];

        float ir0, iz0, in0, ir1, iz1, in1;
        {
            const float* g0 = gi + (size_t)m0 * G3H + j0 + jc0;
            const float* g1 = gi + (size_t)m1 * G3H + j0 + jc0;
            ir0 = g0[0]; iz0 = g0[512]; in0 = g0[1024];
            ir1 = g1[0]; iz1 = g1[512]; in1 = g1[1024];
        }
        __syncthreads();

        for (int s = 0; s < NSTEP; ++s) {
            // gather h_prev via sc1 u64 loads
            const __bf16* hb = Hbuf + (size_t)(s & 1) * NB * HID;
            unsigned long long hq[2][4][2];
#pragma unroll
            for (int mt = 0; mt < 2; ++mt)
#pragma unroll
                for (int kk = 0; kk < 4; ++kk) {
                    const unsigned long long* pp = (const unsigned long long*)
                        (hb + (size_t)(mt * 16 + lane15) * HID + k0 + kk * 32 + quad * 8);
                    hq[mt][kk][0] = __hip_atomic_load(pp, __ATOMIC_RELAXED, __HIP_MEMORY_SCOPE_AGENT);
                    hq[mt][kk][1] = __hip_atomic_load(pp + 1, __ATOMIC_RELAXED, __HIP_MEMORY_SCOPE_AGENT);
                }

            f32x4 acc[2][3];
            f32x4 zz = {0.f, 0.f, 0.f, 0.f};
#pragma unroll
            for (int mt = 0; mt < 2; ++mt)
#pragma unroll
                for (int g = 0; g < 3; ++g) acc[mt][g] = zz;
#pragma unroll
            for (int kk = 0; kk < 4; ++kk) {
                int ks = kk * 32;
                bf16x8 a0 = __builtin_bit_cast(bf16x8, u128{hq[0][kk][0], hq[0][kk][1]});
                bf16x8 a1 = __builtin_bit_cast(bf16x8, u128{hq[1][kk][0], hq[1][kk][1]});
#pragma unroll
                for (int g = 0; g < 3; ++g) {
                    bf16x8 b4 = *(const bf16x8*)(&Wl[(g * 16 + lane15) * 520 + k0 + ks + quad * 8]);
                    acc[0][g] = __builtin_amdgcn_mfma_f32_16x16x32_bf16(a0, b4, acc[0][g], 0, 0, 0);
                    acc[1][g] = __builtin_amdgcn_mfma_f32_16x16x32_bf16(a1, b4, acc[1][g], 0, 0, 0);
                }
            }
#pragma unroll
            for (int mt = 0; mt < 2; ++mt)
#pragma unroll
                for (int g = 0; g < 3; ++g)
#pragma unroll
                    for (int r = 0; r < 4; ++r)
                        CREDp(wave, g, mt * 16 + quad * 4 + r, lane15) = acc[mt][g][r];
            __syncthreads();

            {
                float gr = CREDp(0,0,m0,jc0) + CREDp(1,0,m0,jc0) + CREDp(2,0,m0,jc0) + CREDp(3,0,m0,jc0);
                float gz = CREDp(0,1,m0,jc0) + CREDp(1,1,m0,jc0) + CREDp(2,1,m0,jc0) + CREDp(3,1,m0,jc0);
                float gn = CREDp(0,2,m0,jc0) + CREDp(1,2,m0,jc0) + CREDp(2,2,m0,jc0) + CREDp(3,2,m0,jc0);
                float r = 1.f / (1.f + expf(-(ir0 + gr)));
                float zg = 1.f / (1.f + expf(-(iz0 + gz)));
                float nn = tanhf(in0 + r * (gn + bhn));
                hp0 = (1.f - zg) * nn + zg * hp0;
                HbO[m0][jc0] = (__bf16)hp0;
            }
            {
                float gr = CREDp(0,0,m1,jc0) + CREDp(1,0,m1,jc0) + CREDp(2,0,m1,jc0) + CREDp(3,0,m1,jc0);
                float gz = CREDp(0,1,m1,jc0) + CREDp(1,1,m1,jc0) + CREDp(2,1,m1,jc0) + CREDp(3,1,m1,jc0);
                float gn = CREDp(0,2,m1,jc0) + CREDp(1,2,m1,jc0) + CREDp(2,2,m1,jc0) + CREDp(3,2,m1,jc0);
                float r = 1.f / (1.f + expf(-(ir1 + gr)));
                float zg = 1.f / (1.f + expf(-(iz1 + gz)));
                float nn = tanhf(in1 + r * (gn + bhn));
                hp1 = (1.f - zg) * nn + zg * hp1;
                HbO[m1][jc0] = (__bf16)hp1;
            }
            __syncthreads();

            // publish own 16-col slice (Hbuf ping-pong + Hs) as sc1 u64
            if (tid < 128) {
                int m = tid >> 2, g4 = tid & 3;
                unsigned long long v0 = *(const unsigned short*)&HbO[m][g4 * 4 + 0];
                unsigned long long v1 = *(const unsigned short*)&HbO[m][g4 * 4 + 1];
                unsigned long long v2 = *(const unsigned short*)&HbO[m][g4 * 4 + 2];
                unsigned long long v3 = *(const unsigned short*)&HbO[m][g4 * 4 + 3];
                unsigned long long pk = v0 | (v1 << 16) | (v2 << 32) | (v3 << 48);
                unsigned long long* dst = (unsigned long long*)
                    (Hbuf + (size_t)((s + 1) & 1) * NB * HID + (size_t)m * HID + j0 + g4 * 4);
                __hip_atomic_store(dst, pk, __ATOMIC_RELAXED, __HIP_MEMORY_SCOPE_AGENT);
                unsigned long long* dst2 = (unsigned long long*)
                    (Hs + (size_t)(s * NB + m) * HID + j0 + g4 * 4);
                __hip_atomic_store(dst2, pk, __ATOMIC_RELAXED, __HIP_MEMORY_SCOPE_AGENT);
            }

            // drain publish stores only (gi prefetch not yet issued)
            __builtin_amdgcn_s_waitcnt(0x0f70);
            __syncthreads();

            if (tid == 0)
                __hip_atomic_store(&flags[blk * FLAG_STRIDE], s + 1,
                                   __ATOMIC_RELAXED, __HIP_MEMORY_SCOPE_AGENT);

            // prefetch next step's gi (hidden behind the poll)
            float nir0, niz0, nin0, nir1, niz1, nin1;
            if (s + 1 < NSTEP) {
                const float* g0 = gi + (size_t)((s + 1) * NB + m0) * G3H + j0 + jc0;
                const float* g1 = gi + (size_t)((s + 1) * NB + m1) * G3H + j0 + jc0;
                nir0 = g0[0]; niz0 = g0[512]; nin0 = g0[1024];
                nir1 = g1[0]; niz1 = g1[512]; nin1 = g1[1024];
            } else {
                nir0 = niz0 = nin0 = nir1 = niz1 = nin1 = 0.f;
            }

            if (tid < NBLK_GRU) {
                while (__hip_atomic_load(&flags[tid * FLAG_STRIDE],
                                         __ATOMIC_RELAXED, __HIP_MEMORY_SCOPE_AGENT) < s + 1)
                    __builtin_amdgcn_s_sleep(1);
            }
            __syncthreads();

            if (blk == 0 && tid == 0)
                __hip_atomic_store(progress, s + 1,
                                   __ATOMIC_RELAXED, __HIP_MEMORY_SCOPE_AGENT);

            ir0 = nir0; iz0 = niz0; in0 = nin0;
            ir1 = nir1; iz1 = niz1; in1 = nin1;
        }

        Hfin[(size_t)m0 * HID + j0 + jc0] = hp0;
        Hfin[(size_t)m1 * HID + j0 + jc0] = hp1;

    } else {
        // ================= emit worker =================
        __bf16* As = (__bf16*)smem;             // 256*64*2 = 32768
        __bf16* Bs = (__bf16*)(smem + 32768);   // 128*64*2 = 16384
        const float NINF = -__builtin_inff();

        for (;;) {
            if (tid == 0) {
                int t = __hip_atomic_fetch_add(ticket, 1, __ATOMIC_RELAXED,
                                               __HIP_MEMORY_SCOPE_AGENT);
                tShare = t;
                if (t < NTILE) {
                    int mc = t / NT_V;
                    int need = (mc == 15) ? NSTEP : 8 * (mc + 1);
                    while (__hip_atomic_load(progress, __ATOMIC_RELAXED,
                                             __HIP_MEMORY_SCOPE_AGENT) < need)
                        __builtin_amdgcn_s_sleep(32);
                }
            }
            __syncthreads();
            int t = tShare;
            if (t >= NTILE) break;
            int mc = t / NT_V;
            int nT = t - mc * NT_V;
            int mBase = mc * 256, nBase = nT * 128;

            f32x4 acc[4][8];
            f32x4 z = {0.f, 0.f, 0.f, 0.f};
#pragma unroll
            for (int mi = 0; mi < 4; ++mi)
#pragma unroll
                for (int ni = 0; ni < 8; ++ni) acc[mi][ni] = z;

            for (int kc = 0; kc < 512; kc += 64) {
                __syncthreads();
#pragma unroll
                for (int i = 0; i < 8; ++i) {
                    int c = (wave * 8 + i) * 64 + lane;   // 0..2047
                    int row = c >> 3, ci = c & 7;
                    int cis = ci ^ (row & 7);
                    async16(Hs + (size_t)(mBase + row) * 512 + kc + (cis << 3),
                            As + (wave * 8 + i) * 512);
                }
#pragma unroll
                for (int i = 0; i < 4; ++i) {
                    int c = (wave * 4 + i) * 64 + lane;   // 0..1023
                    int row = c >> 3, ci = c & 7;
                    int cis = ci ^ (row & 7);
                    async16(Wemb + (size_t)(nBase + row) * 512 + kc + (cis << 3),
                            Bs + (wave * 4 + i) * 512);
                }
                __syncthreads();
#pragma unroll
                for (int ks = 0; ks < 64; ks += 32) {
                    int L = (ks >> 3) + quad;
                    bf16x8 a4[4], b4[8];
#pragma unroll
                    for (int mi = 0; mi < 4; ++mi) {
                        int row = wave * 64 + mi * 16 + lane15;
                        a4[mi] = *(const bf16x8*)(As + row * 64 + ((L ^ (row & 7)) << 3));
                    }
#pragma unroll
                    for (int ni = 0; ni < 8; ++ni) {
                        int row = ni * 16 + lane15;
                        b4[ni] = *(const bf16x8*)(Bs + row * 64 + ((L ^ (row & 7)) << 3));
                    }
#pragma unroll
                    for (int mi = 0; mi < 4; ++mi)
#pragma unroll
                        for (int ni = 0; ni < 8; ++ni)
                            acc[mi][ni] = __builtin_amdgcn_mfma_f32_16x16x32_bf16(
                                a4[mi], b4[ni], acc[mi][ni], 0, 0, 0);
                }
            }

            float bv[8];
            bool valid[8];
#pragma unroll
            for (int ni = 0; ni < 8; ++ni) {
                int col = nBase + ni * 16 + lane15;
                valid[ni] = (col < V_SIZE);
                bv[ni] = valid[ni] ? emit_b[col] : 0.0f;
            }
#pragma unroll
            for (int mi = 0; mi < 4; ++mi) {
#pragma unroll
                for (int r = 0; r < 4; ++r) {
                    float vals[8];
                    float vmax = NINF;
#pragma unroll
                    for (int ni = 0; ni < 8; ++ni) {
                        float v = acc[mi][ni][r] + bv[ni];
                        if (!valid[ni]) v = NINF;
                        vals[ni] = v;
                        vmax = fmaxf(vmax, v);
                    }
#pragma unroll
                    for (int off = 1; off < 16; off <<= 1)
                        vmax = fmaxf(vmax, __shfl_xor(vmax, off));
                    float ssum = 0.f;
#pragma unroll
                    for (int ni = 0; ni < 8; ++ni) ssum += expf(vals[ni] - vmax);
#pragma unroll
                    for (int off = 1; off < 16; off <<= 1) ssum += __shfl_xor(ssum, off);
                    if (lane15 == 0) {
                        int m = mBase + wave * 64 + mi * 16 + quad * 4 + r;
                        partials[(size_t)m * NT_V + nT] = make_float2(vmax, ssum);
                    }
                }
            }
        }
    }
}

// ---------------- per-row log-likelihood ----------------
__global__ __launch_bounds__(128) void k_row_ll(const float2* __restrict__ partials,
                                                const __bf16* __restrict__ Hs,
                                                const __bf16* __restrict__ Wemb,
                                                const float* __restrict__ emit_b,
                                                const int* __restrict__ words,
                                                float* __restrict__ lls) {
    int s = blockIdx.x, n = blockIdx.y;
    int m = s * NB + n;
    int tid = threadIdx.x;
    int lane = tid & 63, w = tid >> 6;
    __shared__ float sm[2], ss[2], sd[2];
    const float2* prow = partials + (size_t)m * NT_V;
    float M = -__builtin_inff();
    for (int i = tid; i < NT_V; i += 128) M = fmaxf(M, prow[i].x);
#pragma unroll
    for (int off = 1; off < 64; off <<= 1) M = fmaxf(M, __shfl_xor(M, off));
    if (lane == 0) sm[w] = M;
    __syncthreads();
    M = fmaxf(sm[0], sm[1]);
    float S = 0.f;
    for (int i = tid; i < NT_V; i += 128) {
        float2 p = prow[i];
        S += p.y * expf(p.x - M);
    }
#pragma unroll
    for (int off = 1; off < 64; off <<= 1) S += __shfl_xor(S, off);
    if (lane == 0) ss[w] = S;
    __syncthreads();
    S = ss[0] + ss[1];
    int tw = words[n * TT + s + 1];
    float d = 0.f;
    const __bf16* hr = Hs + (size_t)m * HID;
    const __bf16* wr = Wemb + (size_t)tw * HID;
    for (int k = tid; k < HID; k += 128) d += (float)hr[k] * (float)wr[k];
#pragma unroll
    for (int off = 1; off < 64; off <<= 1) d += __shfl_xor(d, off);
    if (lane == 0) sd[w] = d;
    __syncthreads();
    if (tid == 0) {
        float dt = sd[0] + sd[1];
        lls[m] = dt + emit_b[tw] - (M + logf(S));
    }
}

// ---------------- final reduce ----------------
__global__ __launch_bounds__(128) void k_final(const float* __restrict__ lls,
                                               const float* __restrict__ Hfin,
                                               float* __restrict__ out) {
    int n = blockIdx.x;
    int tid = threadIdx.x;
    float s = 0.f;
    for (int i = tid; i < NSTEP; i += 128) s += lls[i * NB + n];
#pragma unroll
    for (int off = 1; off < 64; off <<= 1) s += __shfl_xor(s, off);
    __shared__ float t2[2];
    if ((tid & 63) == 0) t2[tid >> 6] = s;
    __syncthreads();
    if (tid == 0) out[n] = (t2[0] + t2[1]) / (float)NSTEP;
    for (int i = tid; i < HID; i += 128) out[NB + n * HID + i] = Hfin[(size_t)n * HID + i];
}

// ---------------- launch ----------------
extern "C" void kernel_launch(void* const* d_in, const int* in_sizes, int n_in,
                              void* d_out, int out_size, void* d_ws, size_t ws_size,
                              hipStream_t stream) {
    const int*   words   = (const int*)d_in[0];
    const float* hidden0 = (const float*)d_in[1];
    const float* embed_W = (const float*)d_in[2];
    const float* W_ih    = (const float*)d_in[3];
    const float* W_hh    = (const float*)d_in[4];
    const float* b_ih    = (const float*)d_in[5];
    const float* b_hh    = (const float*)d_in[6];
    const float* emit_W  = (const float*)d_in[7];
    const float* emit_b  = (const float*)d_in[8];
    float* out = (float*)d_out;

    char* p = (char*)d_ws;
    auto alloc = [&](size_t bytes) {
        void* r = (void*)p;
        p += (bytes + 255) & ~(size_t)255;
        return r;
    };
    __bf16* emit_Wb = (__bf16*)alloc((size_t)VPAD * 512 * 2);
    __bf16* Xb      = (__bf16*)alloc((size_t)MPAD * 512 * 2);
    __bf16* Wihb    = (__bf16*)alloc((size_t)G3H * 512 * 2);
    float*  gi      = (float*)alloc((size_t)MPAD * G3H * 4);
    __bf16* Hs      = (__bf16*)alloc((size_t)MPAD * 512 * 2);
    __bf16* Hbuf    = (__bf16*)alloc((size_t)2 * NB * HID * 2);
    float*  Hfin    = (float*)alloc((size_t)NB * HID * 4);
    float2* partials= (float2*)alloc((size_t)MPAD * NT_V * 8);
    float*  lls     = (float*)alloc((size_t)MROWS * 4);
    int*    ctrl    = (int*)alloc(2048 * 4);

    k_prep_emit<<<4096, 256, 0, stream>>>(emit_W, emit_Wb);
    k_prep_x<<<dim3(128, 32), 128, 0, stream>>>(words, embed_W, Xb, Hs);
    k_prep_wih<<<768, 256, 0, stream>>>(W_ih, Wihb);
    k_prep_h0<<<NB + 1, 256, 0, stream>>>(hidden0, Hbuf, ctrl);

    k_gemm_gi<<<dim3(32, 12), 256, 0, stream>>>(Xb, Wihb, b_ih, b_hh, gi);

    k_fused<<<NBLK_GRU + NWORKER, 256, 0, stream>>>(
        W_hh, gi, b_hh, hidden0, Hbuf, Hs, Hfin, emit_Wb, emit_b, partials, ctrl);

    k_row_ll<<<dim3(NSTEP, 32), 128, 0, stream>>>(partials, Hs, emit_Wb, emit_b, words, lls);
    k_final<<<32, 128, 0, stream>>>(lls, Hfin, out);
}